// Round 5
// baseline (384.575 us; speedup 1.0000x reference)
//
#include <hip/hip_runtime.h>
#include <math.h>

#define N_USERS    100000
#define N_ITEMS    50000
#define N_ENTITIES 200000
#define N_REL      20
#define EMB        64
#define HOPS       2
#define MARGIN_CCL 0.8f
#define NUM_NEG    64
#define ANGLE_W    0.1f
#define ANGLE_DROP 0.5f
#define N_EDGES    1000000
#define NNZ        1000000
#define N_TRIPLETS 200000
#define BATCH      4096
#define EPSF       1e-6f

#define TILE1 4096
#define NBUCK 196
#define ACAP  8192
#define HBLK  ((N_EDGES + TILE1 - 1) / TILE1)   // 245
#define P1B   (3 * HBLK)                     // 735
#define KGB   (N_ENTITIES / 32)              // 6250
#define UCFB  (N_USERS / 32)                 // 3125
#define ITEMB ((N_ITEMS + 31) / 32)          // 1563
#define UBB   (BATCH / 32)                   // 128
#define ANGB  (N_TRIPLETS / 32)              // 6250
#define LOSSB (BATCH / 4)                    // 1024
#define CONVE (N_ENTITIES * 16 / 256)        // 12500
#define CONVI (N_ITEMS * 16 / 256)           // 3125

typedef _Float16 half4_t __attribute__((ext_vector_type(4)));
typedef _Float16 half8_t __attribute__((ext_vector_type(8)));
typedef float float8_t __attribute__((ext_vector_type(8)));

__device__ inline float4 h2f(half4_t h) {
    return make_float4((float)h.x, (float)h.y, (float)h.z, (float)h.w);
}
__device__ inline half4_t f2h(float4 f) {
    half4_t h; h.x = (_Float16)f.x; h.y = (_Float16)f.y;
    h.z = (_Float16)f.z; h.w = (_Float16)f.w; return h;
}
__device__ inline float8_t h8_to_f8(half8_t h) { return __builtin_convertvector(h, float8_t); }
__device__ inline half8_t f8_to_h8(float8_t f) { return __builtin_convertvector(f, half8_t); }
__device__ inline half8_t h8_zero() {
    half8_t z;
    #pragma unroll
    for (int i = 0; i < 8; ++i) z[i] = (_Float16)0.0f;
    return z;
}
__device__ inline float sum_sq8(float8_t f) {
    float s = 0.f;
    #pragma unroll
    for (int i = 0; i < 8; ++i) s += f[i] * f[i];
    return s;
}
__device__ inline float dot8(float8_t a, float8_t b) {
    float s = 0.f;
    #pragma unroll
    for (int i = 0; i < 8; ++i) s += a[i] * b[i];
    return s;
}
__device__ inline float8_t f8_from2(float4 lo, float4 hi) {
    float8_t f;
    f[0] = lo.x; f[1] = lo.y; f[2] = lo.z; f[3] = lo.w;
    f[4] = hi.x; f[5] = hi.y; f[6] = hi.z; f[7] = hi.w;
    return f;
}
__device__ inline float grp_red8(float v) {
    v += __shfl_xor(v, 1, 64); v += __shfl_xor(v, 2, 64); v += __shfl_xor(v, 4, 64);
    return v;
}
__device__ inline float dot4(float4 a, float4 b) {
    return a.x * b.x + a.y * b.y + a.z * b.z + a.w * b.w;
}
__device__ inline float grp_red16(float v) {
    v += __shfl_xor(v, 1, 64); v += __shfl_xor(v, 2, 64);
    v += __shfl_xor(v, 4, 64); v += __shfl_xor(v, 8, 64);
    return v;
}
__device__ inline float cross_grp_scalar(float v) {
    v += __shfl_xor(v, 16, 64); v += __shfl_xor(v, 32, 64);
    return v;
}
// val is multiplied as fp16 by all consumers; converting at pack time is
// bit-identical to converting at consume time.
__device__ inline int f32_to_h16bits(float v) {
    _Float16 h = (_Float16)v;
    return (int)__builtin_bit_cast(unsigned short, h);
}
__device__ inline _Float16 h16_from_bits(int b) {
    return __builtin_bit_cast(_Float16, (unsigned short)(b & 0xFFFF));
}

// fp16 angle body: 8-lane groups, 32 triplets/block
__device__ inline void angle_body(int ablk, int t, const half8_t* __restrict__ ent_h,
                                  const int* __restrict__ th, const int* __restrict__ tt,
                                  float* sb, float* __restrict__ l2blk) {
    int o = t & 7;
    int grp = t >> 3;
    int trip = ablk * 32 + grp;
    int h = th[trip], t2 = tt[trip];
    float8_t hv = h8_to_f8(ent_h[h * 8 + o]);
    float8_t tv = h8_to_f8(ent_h[t2 * 8 + o]);
    hv *= ANGLE_DROP;
    tv *= ANGLE_DROP;
    float8_t dv = hv - tv;
    float s_hh = grp_red8(sum_sq8(hv));
    float s_tt = grp_red8(sum_sq8(tv));
    float s_ht = grp_red8(dot8(hv, tv));
    float s_dd = grp_red8(sum_sq8(dv));
    if (o == 0) {
        float nu = sqrtf(s_hh);
        float ed = sqrtf(s_dd);
        float sqnu = fminf(fmaxf(s_hh, 0.0f), 1.0f - EPSF);
        float ha_arg = fminf(fmaxf(0.1f * (1.0f - sqnu) / sqrtf(sqnu), -1.0f + EPSF), 1.0f - EPSF);
        float half_ap = asinf(ha_arg);
        float num = s_ht * (1.0f + s_hh) - s_hh * (1.0f + s_tt);
        float den = nu * ed * sqrtf(fmaxf(1.0f + s_tt * s_hh - 2.0f * s_ht, EPSF)) + EPSF;
        float ang = acosf(fminf(fmaxf(num / den, -1.0f + EPSF), 1.0f - EPSF));
        sb[grp] = fmaxf(ang - half_ap, 0.0f);
    }
    __syncthreads();
    if (t == 0) {
        float tot = 0.f;
        #pragma unroll
        for (int i = 0; i < 32; ++i) tot += sb[i];
        l2blk[ablk] = tot;
    }
}

// -------------- phase 1: bucket-grouped placement (+ fp32->fp16 conversions) -----------
// relative cursors (memset to 0 by host-side hipMemsetAsync); arena base = bucket*ACAP
// Two passes only: hist (+scan +gbase), then DIRECT global placement at
// pos = gbase[bkt] + (sp - lstart[bkt])  — identical slot mapping to the old
// staged+scatter version (staging index sp == scatter index j), one fewer pass,
// no 16 KB LDS staging buffer.
__global__ void __launch_bounds__(256) phase1_sort(
        const int* __restrict__ head, const int* __restrict__ tail,
        const int* __restrict__ etype, const int* __restrict__ rows,
        const int* __restrict__ cols, const float* __restrict__ vals,
        int* __restrict__ bcur_e, int* __restrict__ bcur_u, int* __restrict__ bcur_i,
        int* __restrict__ keys_ping, int* __restrict__ kg_ping,
        int2* __restrict__ u_ping, int2* __restrict__ i_ping,
        const float4* __restrict__ ent0, const float4* __restrict__ cf0,
        half4_t* __restrict__ ent_a4, half4_t* __restrict__ cf16a4) {
    __shared__ int lhist[256], lstart[256], lcur[256], gbase[256];
    __shared__ int wsum[4], wpre[4];
    int bx = blockIdx.x, t = threadIdx.x;
    if (bx >= P1B) {
        // fp32->fp16 table conversions (streaming; overlap the latency-bound sort)
        int cb = bx - P1B;
        if (cb < CONVE) { int i = cb * 256 + t; ent_a4[i] = f2h(ent0[i]); }
        else            { int i = (cb - CONVE) * 256 + t; cf16a4[i] = f2h(cf0[i]); }
        return;
    }
    int seg = bx / HBLK;
    int tb  = bx % HBLK;
    int tstart = tb * TILE1;
    int valid = min(TILE1, N_EDGES - tstart);
    const int* karr = (seg == 0) ? head : (seg == 1) ? rows : cols;
    int shift = (seg == 0) ? 10 : (seg == 1) ? 9 : 8;
    int* bcur = (seg == 0) ? bcur_e : (seg == 1) ? bcur_u : bcur_i;
    lhist[t] = 0;
    __syncthreads();
    for (int i = t; i < valid; i += 256) atomicAdd(&lhist[karr[tstart + i] >> shift], 1);
    __syncthreads();
    int v = lhist[t];
    int lane = t & 63, wv = t >> 6;
    int sc = v;
    #pragma unroll
    for (int d = 1; d < 64; d <<= 1) {
        int x = __shfl_up(sc, d, 64);
        if (lane >= d) sc += x;
    }
    if (lane == 63) wsum[wv] = sc;
    __syncthreads();
    if (t == 0) {
        int a = 0;
        #pragma unroll
        for (int i = 0; i < 4; ++i) { wpre[i] = a; a += wsum[i]; }
    }
    __syncthreads();
    int excl = sc + wpre[wv] - v;
    lstart[t] = excl;
    lcur[t] = excl;
    gbase[t] = t * ACAP + atomicAdd(&bcur[t], v);
    __syncthreads();
    if (seg == 0) {
        for (int i = t; i < valid; i += 256) {
            int h = head[tstart + i];
            int p = tail[tstart + i] | ((etype[tstart + i] - 1) << 18);
            int b = h >> 10;
            int sp = atomicAdd(&lcur[b], 1);
            int pos = gbase[b] + (sp - lstart[b]);
            keys_ping[pos] = h;
            kg_ping[pos] = p;
        }
    } else {
        int2* pay = (seg == 1) ? u_ping : i_ping;
        for (int i = t; i < valid; i += 256) {
            int k = karr[tstart + i];
            int bkt = k >> shift;
            int px;
            if (seg == 1) px = cols[tstart + i] | ((k & 511) << 16);
            else          px = rows[tstart + i] | ((k & 255) << 17);
            int py = f32_to_h16bits(vals[tstart + i]);
            int sp = atomicAdd(&lcur[bkt], 1);
            int pos = gbase[bkt] + (sp - lstart[bkt]);
            pay[pos] = make_int2(px, py);
        }
    }
}

// ------------- phase 2: row offsets + ping->pong scatter (+ angle overlap) -------------
__global__ void __launch_bounds__(256) phase2_angle(
        const int* __restrict__ bcur_e, const int* __restrict__ keys_ping,
        const int* __restrict__ kg_ping, int* __restrict__ kg_pack, int* __restrict__ off_e,
        const int* __restrict__ bcur_u, const int2* __restrict__ u_ping,
        int2* __restrict__ u_pack, int* __restrict__ off_u,
        const int* __restrict__ bcur_i, const int2* __restrict__ i_ping,
        int2* __restrict__ i_pack, int* __restrict__ off_i,
        const half8_t* __restrict__ ent_a, const int* __restrict__ th,
        const int* __restrict__ tt, float* __restrict__ l2blk) {
    __shared__ int hist[1024];
    __shared__ int wsum[4], wpre[4];
    __shared__ float sb[32];
    int t = threadIdx.x;
    if (blockIdx.x >= 3 * NBUCK) {
        angle_body(blockIdx.x - 3 * NBUCK, t, ent_a, th, tt, sb, l2blk);
        return;
    }
    int seg = blockIdx.x / NBUCK;
    int b   = blockIdx.x % NBUCK;
    int bins  = (seg == 0) ? 1024 : (seg == 1) ? 512 : 256;
    int shift = (seg == 0) ? 10 : (seg == 1) ? 9 : 8;
    int n_rows = (seg == 0) ? N_ENTITIES : (seg == 1) ? N_USERS : N_ITEMS;
    const int* bcur = (seg == 0) ? bcur_e : (seg == 1) ? bcur_u : bcur_i;
    int* off = (seg == 0) ? off_e : (seg == 1) ? off_u : off_i;
    int rs = b << shift;
    int re = min(rs + bins, n_rows);
    int nr = re - rs;
    int base = b * ACAP;
    int len = bcur[b];                       // relative cursor = count
    for (int r = t; r < bins; r += 256) hist[r] = 0;
    __syncthreads();
    if (seg == 0) {
        for (int j = t; j < len; j += 256) atomicAdd(&hist[keys_ping[base + j] - rs], 1);
    } else if (seg == 1) {
        for (int j = t; j < len; j += 256) atomicAdd(&hist[(u_ping[base + j].x >> 16) & 511], 1);
    } else {
        for (int j = t; j < len; j += 256) atomicAdd(&hist[(i_ping[base + j].x >> 17) & 255], 1);
    }
    __syncthreads();
    int own = bins >> 8;
    int c[4]; int tot = 0;
    #pragma unroll
    for (int i = 0; i < 4; ++i) { c[i] = (i < own) ? hist[t * own + i] : 0; tot += c[i]; }
    int lane = t & 63, wv = t >> 6;
    int sc = tot;
    #pragma unroll
    for (int d = 1; d < 64; d <<= 1) {
        int x = __shfl_up(sc, d, 64);
        if (lane >= d) sc += x;
    }
    if (lane == 63) wsum[wv] = sc;
    __syncthreads();
    if (t == 0) {
        int a = 0;
        #pragma unroll
        for (int i = 0; i < 4; ++i) { wpre[i] = a; a += wsum[i]; }
    }
    __syncthreads();
    int run = sc + wpre[wv] - tot;
    #pragma unroll
    for (int i = 0; i < 4; ++i) { if (i < own) { hist[t * own + i] = run; run += c[i]; } }
    __syncthreads();
    for (int r = t; r < nr; r += 256) off[rs + b + r] = base + hist[r];
    if (t == 0) off[rs + b + nr] = base + len;
    __syncthreads();
    if (seg == 0) {
        for (int j = t; j < len; j += 256) {
            int k = keys_ping[base + j];
            int slot = atomicAdd(&hist[k - rs], 1);
            kg_pack[base + slot] = kg_ping[base + j];
        }
    } else if (seg == 1) {
        for (int j = t; j < len; j += 256) {
            int2 p = u_ping[base + j];
            int slot = atomicAdd(&hist[(p.x >> 16) & 511], 1);
            u_pack[base + slot] = p;
        }
    } else {
        for (int j = t; j < len; j += 256) {
            int2 p = i_ping[base + j];
            int slot = atomicAdd(&hist[(p.x >> 17) & 255], 1);
            i_pack[base + slot] = p;
        }
    }
}

// ------------------------------ hop bodies ------------------------------
// 4-edge unroll: gathers issued together for MLP; fp16 accumulation order
// (strictly ascending k, one add per edge) identical to the 2-unroll version.
__device__ inline void kg0_body(int bid, int t, const int* __restrict__ off,
                                const int* __restrict__ pack, half8_t* srel,
                                const float* __restrict__ relw,
                                const half8_t* __restrict__ src, half8_t* __restrict__ dst,
                                half8_t* __restrict__ res, const float4* __restrict__ res_init) {
    if (t < (N_REL - 1) * 8) {
        int rel = t >> 3, o = t & 7;
        const float4* r4 = (const float4*)relw;
        srel[rel * 9 + o] = f8_to_h8(f8_from2(r4[rel * 16 + o * 2], r4[rel * 16 + o * 2 + 1]));
    }
    __syncthreads();
    int row = bid * 32 + (t >> 3);
    int o = t & 7;
    int idx = row + (row >> 10);
    int s = off[idx], e = off[idx + 1];
    half8_t acc = h8_zero();
    int k = s;
    for (; k + 4 <= e; k += 4) {
        int p0 = pack[k], p1 = pack[k + 1], p2 = pack[k + 2], p3 = pack[k + 3];
        half8_t a0 = src[(p0 & 0x3FFFF) * 8 + o];
        half8_t a1 = src[(p1 & 0x3FFFF) * 8 + o];
        half8_t a2 = src[(p2 & 0x3FFFF) * 8 + o];
        half8_t a3 = src[(p3 & 0x3FFFF) * 8 + o];
        acc += a0 * srel[(p0 >> 18) * 9 + o];
        acc += a1 * srel[(p1 >> 18) * 9 + o];
        acc += a2 * srel[(p2 >> 18) * 9 + o];
        acc += a3 * srel[(p3 >> 18) * 9 + o];
    }
    for (; k < e; ++k) {
        int p0 = pack[k];
        acc += src[(p0 & 0x3FFFF) * 8 + o] * srel[(p0 >> 18) * 9 + o];
    }
    float8_t f = h8_to_f8(acc);
    f *= 1.0f / fmaxf((float)(e - s), 1.0f);
    float ss = grp_red8(sum_sq8(f));
    f *= 1.0f / fmaxf(sqrtf(ss), 1e-12f);
    dst[row * 8 + o] = f8_to_h8(f);
    if (row < N_ITEMS) {
        float8_t rr = f8_from2(res_init[row * 16 + o * 2], res_init[row * 16 + o * 2 + 1]);
        rr += f;
        res[row * 8 + o] = f8_to_h8(rr);
    }
}

__device__ inline void kg2_body(int bid, int t, const int* __restrict__ off,
                                const int* __restrict__ pack, half8_t* srel,
                                const float* __restrict__ relw,
                                const half8_t* __restrict__ src, half8_t* __restrict__ res) {
    if (t < (N_REL - 1) * 8) {
        int rel = t >> 3, o = t & 7;
        const float4* r4 = (const float4*)relw;
        srel[rel * 9 + o] = f8_to_h8(f8_from2(r4[rel * 16 + o * 2], r4[rel * 16 + o * 2 + 1]));
    }
    __syncthreads();
    int row = bid * 32 + (t >> 3);
    if (row >= N_ITEMS) return;
    int o = t & 7;
    int idx = row + (row >> 10);
    int s = off[idx], e = off[idx + 1];
    half8_t acc = h8_zero();
    int k = s;
    for (; k + 4 <= e; k += 4) {
        int p0 = pack[k], p1 = pack[k + 1], p2 = pack[k + 2], p3 = pack[k + 3];
        half8_t a0 = src[(p0 & 0x3FFFF) * 8 + o];
        half8_t a1 = src[(p1 & 0x3FFFF) * 8 + o];
        half8_t a2 = src[(p2 & 0x3FFFF) * 8 + o];
        half8_t a3 = src[(p3 & 0x3FFFF) * 8 + o];
        acc += a0 * srel[(p0 >> 18) * 9 + o];
        acc += a1 * srel[(p1 >> 18) * 9 + o];
        acc += a2 * srel[(p2 >> 18) * 9 + o];
        acc += a3 * srel[(p3 >> 18) * 9 + o];
    }
    for (; k < e; ++k) {
        int p0 = pack[k];
        acc += src[(p0 & 0x3FFFF) * 8 + o] * srel[(p0 >> 18) * 9 + o];
    }
    float8_t f = h8_to_f8(acc);
    f *= 1.0f / fmaxf((float)(e - s), 1.0f);
    float ss = grp_red8(sum_sq8(f));
    f *= 1.0f / fmaxf(sqrtf(ss), 1e-12f);
    float8_t rr = h8_to_f8(res[row * 8 + o]);
    rr += f;
    float s2 = grp_red8(sum_sq8(rr));
    rr *= 1.0f / fmaxf(sqrtf(s2), 1e-12f);
    res[row * 8 + o] = f8_to_h8(rr);
}

__device__ inline void ucf_body(int bid, int t, const int* __restrict__ off,
                                const int2* __restrict__ u_pack,
                                const half8_t* __restrict__ cf16,
                                half8_t* __restrict__ ucf) {
    int row = bid * 32 + (t >> 3);
    int o = t & 7;
    int idx = row + (row >> 9);
    int s = off[idx], e = off[idx + 1];
    half8_t acc = h8_zero();
    int k = s;
    for (; k + 4 <= e; k += 4) {
        int2 p0 = u_pack[k], p1 = u_pack[k + 1], p2 = u_pack[k + 2], p3 = u_pack[k + 3];
        half8_t c0 = cf16[(p0.x & 0xFFFF) * 8 + o];
        half8_t c1 = cf16[(p1.x & 0xFFFF) * 8 + o];
        half8_t c2 = cf16[(p2.x & 0xFFFF) * 8 + o];
        half8_t c3 = cf16[(p3.x & 0xFFFF) * 8 + o];
        acc += c0 * h16_from_bits(p0.y);
        acc += c1 * h16_from_bits(p1.y);
        acc += c2 * h16_from_bits(p2.y);
        acc += c3 * h16_from_bits(p3.y);
    }
    for (; k < e; ++k) {
        int2 p0 = u_pack[k];
        acc += cf16[(p0.x & 0xFFFF) * 8 + o] * h16_from_bits(p0.y);
    }
    ucf[row * 8 + o] = acc;
}

__device__ inline void ubatch_body(int bid, int t, const int* __restrict__ user,
                                   const int* __restrict__ off,
                                   const int2* __restrict__ u_pack,
                                   const half8_t* __restrict__ ent_a,
                                   const half8_t* __restrict__ ent_b,
                                   const float4* __restrict__ usr0f,
                                   half8_t* __restrict__ usr_b) {
    int g = t >> 3, o = t & 7;
    int b = bid * 32 + g;
    int uid = user[b];
    int idx = uid + (uid >> 9);
    int s = off[idx], e = off[idx + 1];
    half8_t acc1 = h8_zero(), acc2 = h8_zero();
    int k = s;
    for (; k + 4 <= e; k += 4) {
        int2 p0 = u_pack[k], p1 = u_pack[k + 1], p2 = u_pack[k + 2], p3 = u_pack[k + 3];
        int c0 = (p0.x & 0xFFFF) * 8 + o;
        int c1 = (p1.x & 0xFFFF) * 8 + o;
        int c2 = (p2.x & 0xFFFF) * 8 + o;
        int c3 = (p3.x & 0xFFFF) * 8 + o;
        half8_t ea0 = ent_a[c0], eb0 = ent_b[c0];
        half8_t ea1 = ent_a[c1], eb1 = ent_b[c1];
        half8_t ea2 = ent_a[c2], eb2 = ent_b[c2];
        half8_t ea3 = ent_a[c3], eb3 = ent_b[c3];
        _Float16 v0 = h16_from_bits(p0.y);
        _Float16 v1 = h16_from_bits(p1.y);
        _Float16 v2 = h16_from_bits(p2.y);
        _Float16 v3 = h16_from_bits(p3.y);
        acc1 += ea0 * v0; acc2 += eb0 * v0;
        acc1 += ea1 * v1; acc2 += eb1 * v1;
        acc1 += ea2 * v2; acc2 += eb2 * v2;
        acc1 += ea3 * v3; acc2 += eb3 * v3;
    }
    for (; k < e; ++k) {
        int2 p0 = u_pack[k];
        int c0 = (p0.x & 0xFFFF) * 8 + o;
        _Float16 v0 = h16_from_bits(p0.y);
        acc1 += ent_a[c0] * v0;
        acc2 += ent_b[c0] * v0;
    }
    float8_t f1 = h8_to_f8(acc1);
    float ss1 = grp_red8(sum_sq8(f1));
    f1 *= 1.0f / fmaxf(sqrtf(ss1), 1e-12f);
    float8_t u0 = f8_from2(usr0f[uid * 16 + o * 2], usr0f[uid * 16 + o * 2 + 1]);
    float8_t r1 = h8_to_f8(f8_to_h8(u0 + f1));   // fp16 round-trip (matches hop-1 store)
    float8_t f2 = h8_to_f8(acc2);
    float ss2 = grp_red8(sum_sq8(f2));
    f2 *= 1.0f / fmaxf(sqrtf(ss2), 1e-12f);
    float8_t r = r1 + f2;
    float s3 = grp_red8(sum_sq8(r));
    r *= 1.0f / fmaxf(sqrtf(s3), 1e-12f);
    usr_b[b * 8 + o] = f8_to_h8(r);
}

__device__ inline void item_body(int bid, int t, const int* __restrict__ off,
                                 const int2* __restrict__ i_pack,
                                 const half8_t* __restrict__ ucf,
                                 half8_t* __restrict__ cf_nxt, half8_t* __restrict__ res,
                                 const float4* __restrict__ res_init, int first, int last) {
    int row = bid * 32 + (t >> 3);
    int o = t & 7;
    if (row >= N_ITEMS) return;
    int idx = row + (row >> 8);
    int s = off[idx], e = off[idx + 1];
    half8_t acc = h8_zero();
    int k = s;
    for (; k + 4 <= e; k += 4) {
        int2 p0 = i_pack[k], p1 = i_pack[k + 1], p2 = i_pack[k + 2], p3 = i_pack[k + 3];
        half8_t c0 = ucf[(p0.x & 0x1FFFF) * 8 + o];
        half8_t c1 = ucf[(p1.x & 0x1FFFF) * 8 + o];
        half8_t c2 = ucf[(p2.x & 0x1FFFF) * 8 + o];
        half8_t c3 = ucf[(p3.x & 0x1FFFF) * 8 + o];
        acc += c0 * h16_from_bits(p0.y);
        acc += c1 * h16_from_bits(p1.y);
        acc += c2 * h16_from_bits(p2.y);
        acc += c3 * h16_from_bits(p3.y);
    }
    for (; k < e; ++k) {
        int2 p0 = i_pack[k];
        acc += ucf[(p0.x & 0x1FFFF) * 8 + o] * h16_from_bits(p0.y);
    }
    float8_t f = h8_to_f8(acc);
    float ss = grp_red8(sum_sq8(f));
    f *= 1.0f / fmaxf(sqrtf(ss), 1e-12f);
    if (!last) cf_nxt[row * 8 + o] = f8_to_h8(f);
    float8_t rr;
    if (first) rr = f8_from2(res_init[row * 16 + o * 2], res_init[row * 16 + o * 2 + 1]);
    else       rr = h8_to_f8(res[row * 8 + o]);
    rr += f;
    if (last) {
        float s2 = grp_red8(sum_sq8(rr));
        rr *= 1.0f / fmaxf(sqrtf(s2), 1e-12f);
    }
    res[row * 8 + o] = f8_to_h8(rr);
}

// loss halves — 16 negatives per round for MLP; accumulation order unchanged
__device__ inline void loss_ent_body(int b, int t,
                                     const int* __restrict__ pos, const int* __restrict__ neg,
                                     const half4_t* __restrict__ usrb4,
                                     const half4_t* __restrict__ ent4,
                                     float* __restrict__ dpe, float* __restrict__ l1pe) {
    int lane = t & 63;
    int g = lane >> 4, q = lane & 15;
    int pid = pos[b];
    float4 u = h2f(usrb4[b * 16 + q]);
    float4 p = h2f(ent4[pid * 16 + q]);
    float dpe_v = grp_red16(dot4(u, p));
    float sum_n = 0.f, cnt_n = 0.f;
    const int* nb = neg + b * NUM_NEG;
    for (int j = 0; j < NUM_NEG; j += 16) {
        int n0 = nb[j + g], n1 = nb[j + 4 + g], n2 = nb[j + 8 + g], n3 = nb[j + 12 + g];
        float4 e0 = h2f(ent4[n0 * 16 + q]);
        float4 e1 = h2f(ent4[n1 * 16 + q]);
        float4 e2 = h2f(ent4[n2 * 16 + q]);
        float4 e3 = h2f(ent4[n3 * 16 + q]);
        float dn0 = grp_red16(dot4(u, e0));
        float dn1 = grp_red16(dot4(u, e1));
        float dn2 = grp_red16(dot4(u, e2));
        float dn3 = grp_red16(dot4(u, e3));
        float s0 = fmaxf(dn0 - MARGIN_CCL, 0.f); sum_n += s0; if (s0 > 0.f) cnt_n += 1.f;
        float s1 = fmaxf(dn1 - MARGIN_CCL, 0.f); sum_n += s1; if (s1 > 0.f) cnt_n += 1.f;
        float s2 = fmaxf(dn2 - MARGIN_CCL, 0.f); sum_n += s2; if (s2 > 0.f) cnt_n += 1.f;
        float s3 = fmaxf(dn3 - MARGIN_CCL, 0.f); sum_n += s3; if (s3 > 0.f) cnt_n += 1.f;
    }
    sum_n = cross_grp_scalar(sum_n); cnt_n = cross_grp_scalar(cnt_n);
    if (lane == 0) {
        dpe[b] = dpe_v;
        l1pe[b] = sum_n / (cnt_n + 1e-5f);
    }
}

__global__ void __launch_bounds__(256) loss_cf_kernel(
        const int* __restrict__ pos, const int* __restrict__ neg,
        const half4_t* __restrict__ usrb4, const half4_t* __restrict__ cf4,
        const float* __restrict__ dpe, const float* __restrict__ l1pe,
        float* __restrict__ l1p) {
    int b = blockIdx.x * 4 + (threadIdx.x >> 6);
    int lane = threadIdx.x & 63;
    int g = lane >> 4, q = lane & 15;
    int pid = pos[b];
    float4 u = h2f(usrb4[b * 16 + q]);
    float4 pc = h2f(cf4[pid * 16 + q]);
    float dpc = grp_red16(dot4(u, pc));
    float sum_c = 0.f, cnt_c = 0.f;
    const int* nb = neg + b * NUM_NEG;
    for (int j = 0; j < NUM_NEG; j += 16) {
        int n0 = nb[j + g], n1 = nb[j + 4 + g], n2 = nb[j + 8 + g], n3 = nb[j + 12 + g];
        float4 e0 = h2f(cf4[n0 * 16 + q]);
        float4 e1 = h2f(cf4[n1 * 16 + q]);
        float4 e2 = h2f(cf4[n2 * 16 + q]);
        float4 e3 = h2f(cf4[n3 * 16 + q]);
        float dc0 = grp_red16(dot4(u, e0));
        float dc1 = grp_red16(dot4(u, e1));
        float dc2 = grp_red16(dot4(u, e2));
        float dc3 = grp_red16(dot4(u, e3));
        float t0 = fmaxf(dc0 - MARGIN_CCL, 0.f); sum_c += t0; if (t0 > 0.f) cnt_c += 1.f;
        float t1 = fmaxf(dc1 - MARGIN_CCL, 0.f); sum_c += t1; if (t1 > 0.f) cnt_c += 1.f;
        float t2 = fmaxf(dc2 - MARGIN_CCL, 0.f); sum_c += t2; if (t2 > 0.f) cnt_c += 1.f;
        float t3 = fmaxf(dc3 - MARGIN_CCL, 0.f); sum_c += t3; if (t3 > 0.f) cnt_c += 1.f;
    }
    sum_c = cross_grp_scalar(sum_c); cnt_c = cross_grp_scalar(cnt_c);
    if (lane == 0) {
        float ui_pos = fmaxf(2.0f - dpe[b] - dpc, 0.0f);
        l1p[b] = ui_pos + l1pe[b] + sum_c / (cnt_c + 1e-5f);
    }
}

// --------------------------- fused launches ---------------------------
// kg0 (full) + ucf0 (cf-only, all users)
__global__ void __launch_bounds__(256) fused_h0(
        const int* __restrict__ off_e, const int* __restrict__ kg_pack,
        const float* __restrict__ relw, const half8_t* __restrict__ ent_a,
        half8_t* __restrict__ ent_b, half8_t* __restrict__ ent_res,
        const float4* __restrict__ ent0f,
        const int* __restrict__ off_u, const int2* __restrict__ u_pack,
        const half8_t* __restrict__ cf16_a, half8_t* __restrict__ ucf) {
    __shared__ half8_t srel[(N_REL - 1) * 9];
    int bx = blockIdx.x, t = threadIdx.x;
    if (bx < KGB) {
        kg0_body(bx, t, off_e, kg_pack, srel, relw, ent_a, ent_b, ent_res, ent0f);
    } else {
        ucf_body(bx - KGB, t, off_u, u_pack, cf16_a, ucf);
    }
}

// kg1 (item rows only) + item0 + batch-user embedding
__global__ void __launch_bounds__(256) fused_ik(
        const int* __restrict__ off_e, const int* __restrict__ kg_pack,
        const float* __restrict__ relw, const half8_t* __restrict__ ent_b,
        half8_t* __restrict__ ent_res,
        const int* __restrict__ off_i, const int2* __restrict__ i_pack,
        const half8_t* __restrict__ ucf, half8_t* __restrict__ cf16_b,
        half8_t* __restrict__ cf_res, const float4* __restrict__ cf0f,
        const int* __restrict__ user, const int* __restrict__ off_u,
        const int2* __restrict__ u_pack, const half8_t* __restrict__ ent_a,
        const float4* __restrict__ usr0f, half8_t* __restrict__ usr_b) {
    __shared__ half8_t srel[(N_REL - 1) * 9];
    int bx = blockIdx.x, t = threadIdx.x;
    if (bx < ITEMB) {
        kg2_body(bx, t, off_e, kg_pack, srel, relw, ent_b, ent_res);
    } else if (bx < 2 * ITEMB) {
        item_body(bx - ITEMB, t, off_i, i_pack, ucf, cf16_b, cf_res, cf0f, 1, 0);
    } else {
        ubatch_body(bx - 2 * ITEMB, t, user, off_u, u_pack, ent_a, ent_b, usr0f, usr_b);
    }
}

// ucf hop-1 (from cf1) + ent-half loss
__global__ void __launch_bounds__(256) fused_u1_loss(
        const int* __restrict__ off_u, const int2* __restrict__ u_pack,
        const half8_t* __restrict__ cf16_b, half8_t* __restrict__ ucf,
        const int* __restrict__ pos, const int* __restrict__ neg,
        const half4_t* __restrict__ usrb4, const half4_t* __restrict__ ent4,
        float* __restrict__ dpe, float* __restrict__ l1pe) {
    int bx = blockIdx.x, t = threadIdx.x;
    if (bx < UCFB) {
        ucf_body(bx, t, off_u, u_pack, cf16_b, ucf);
    } else {
        int b = (bx - UCFB) * 4 + (t >> 6);
        loss_ent_body(b, t, pos, neg, usrb4, ent4, dpe, l1pe);
    }
}

__global__ void __launch_bounds__(256) item_h1(
        const int* __restrict__ off_i, const int2* __restrict__ i_pack,
        const half8_t* __restrict__ ucf, half8_t* __restrict__ cf_res,
        const float4* __restrict__ cf0f) {
    item_body(blockIdx.x, threadIdx.x, off_i, i_pack, ucf, (half8_t*)0, cf_res, cf0f, 0, 1);
}

__global__ void finalize_kernel(const float* __restrict__ l1p, const float* __restrict__ l2b,
                                float* __restrict__ out) {
    __shared__ float sb[1024];
    float a1 = 0.f;
    for (int i = threadIdx.x; i < BATCH; i += 1024) a1 += l1p[i];
    float a2 = 0.f;
    for (int i = threadIdx.x; i < ANGB; i += 1024) a2 += l2b[i];
    sb[threadIdx.x] = a1 / (float)BATCH + ANGLE_W * a2 / (float)N_TRIPLETS;
    __syncthreads();
    for (int s = 512; s > 0; s >>= 1) {
        if (threadIdx.x < s) sb[threadIdx.x] += sb[threadIdx.x + s];
        __syncthreads();
    }
    if (threadIdx.x == 0) out[0] = sb[0];
}

extern "C" void kernel_launch(void* const* d_in, const int* in_sizes, int n_in,
                              void* d_out, int out_size, void* d_ws, size_t ws_size,
                              hipStream_t stream) {
    const float* all_embed = (const float*)d_in[0];
    const float* item_cf0  = (const float*)d_in[1];
    const float* relw      = (const float*)d_in[2];
    const float* vals      = (const float*)d_in[3];
    const int* user        = (const int*)d_in[4];
    const int* pos_item    = (const int*)d_in[5];
    const int* neg_item    = (const int*)d_in[6];
    const int* edge_head   = (const int*)d_in[7];
    const int* edge_tail   = edge_head + N_EDGES;
    const int* etype       = (const int*)d_in[8];
    const int* irows       = (const int*)d_in[9];
    const int* icols       = (const int*)d_in[10];
    const int* th          = (const int*)d_in[11];
    const int* tt          = (const int*)d_in[12];
    float* out             = (float*)d_out;

    char* base = (char*)d_ws;
    size_t woff = 0;
    auto alloc = [&](size_t bytes) -> void* {
        void* p = base + woff;
        woff = (woff + bytes + 255) & ~(size_t)255;
        return p;
    };
    const size_t ping_ui = (size_t)NBUCK * ACAP * 8;    // 12,845,056 B
    const size_t ping_kg = (size_t)NBUCK * ACAP * 4;    // 6,422,528 B

    half8_t* ent_a   = (half8_t*)alloc((size_t)N_ENTITIES * EMB * 2);
    // ent_b hosts the u/i ping arenas before fused_h0 writes it (bumped to fit both)
    half8_t* ent_b   = (half8_t*)alloc(2 * ping_ui);
    half8_t* cf16_a  = (half8_t*)alloc((size_t)N_ITEMS * EMB * 2);
    // cf16_b hosts the kg payload ping before fused_ik writes it (bumped)
    half8_t* cf16_b  = (half8_t*)alloc(ping_kg);
    // ucf hosts the kg keys ping before fused_h0 writes it (12.8 MB >= 6.42 MB)
    half8_t* ucf     = (half8_t*)alloc((size_t)N_USERS * EMB * 2);
    half8_t* ent_res = (half8_t*)alloc((size_t)N_ITEMS * EMB * 2);
    half8_t* cf_res  = (half8_t*)alloc((size_t)N_ITEMS * EMB * 2);
    half8_t* usr_b   = (half8_t*)alloc((size_t)BATCH * EMB * 2);
    int2* u_pack     = (int2*)alloc(ping_ui);
    int2* i_pack     = (int2*)alloc(ping_ui);
    int* kg_pack     = (int*)alloc(ping_kg);
    float* l1p       = (float*)alloc((size_t)BATCH * 4);
    float* dpe       = (float*)alloc((size_t)BATCH * 4);
    float* l1pe      = (float*)alloc((size_t)BATCH * 4);
    float* l2blk     = (float*)alloc((size_t)ANGB * 4);
    int* off_e       = (int*)alloc((size_t)(N_ENTITIES + NBUCK + 1) * 4);
    int* off_u       = (int*)alloc((size_t)(N_USERS + NBUCK + 1) * 4);
    int* off_i       = (int*)alloc((size_t)(N_ITEMS + NBUCK + 1) * 4);
    int* bcur_all    = (int*)alloc(3 * 256 * 4);
    int* bcur_e      = bcur_all;
    int* bcur_u      = bcur_all + 256;
    int* bcur_i      = bcur_all + 512;

    // ping aliases (lifetimes: written phase1, read phase2, dead before host write)
    int2* u_ping   = (int2*)ent_b;
    int2* i_ping   = (int2*)((char*)ent_b + ping_ui);
    int* kg_ping   = (int*)cf16_b;
    int* keys_ping = (int*)ucf;

    const float* ent0 = all_embed + (size_t)N_USERS * EMB;

    // 1) zero relative arena cursors (capture-safe async memset)
    hipMemsetAsync(bcur_all, 0, 3 * 256 * 4, stream);
    // 2) phase 1 placement into pings + fp32->fp16 conversions (overlapped)
    phase1_sort<<<P1B + CONVE + CONVI, 256, 0, stream>>>(
        edge_head, edge_tail, etype, irows, icols, vals,
        bcur_e, bcur_u, bcur_i, keys_ping, kg_ping, u_ping, i_ping,
        (const float4*)ent0, (const float4*)item_cf0, (half4_t*)ent_a, (half4_t*)cf16_a);
    // 3) phase 2: row offsets + ping->pong scatter, angle blocks as filler
    phase2_angle<<<3 * NBUCK + ANGB, 256, 0, stream>>>(
        bcur_e, keys_ping, kg_ping, kg_pack, off_e,
        bcur_u, u_ping, u_pack, off_u,
        bcur_i, i_ping, i_pack, off_i,
        (const half8_t*)ent_a, th, tt, l2blk);
    // 4) kg0 (full) + ucf0
    fused_h0<<<KGB + UCFB, 256, 0, stream>>>(
        off_e, kg_pack, relw, ent_a, ent_b, ent_res, (const float4*)ent0,
        off_u, u_pack, cf16_a, ucf);
    // 5) kg1 (items only) + item0 + batch-user embedding
    fused_ik<<<2 * ITEMB + UBB, 256, 0, stream>>>(
        off_e, kg_pack, relw, ent_b, ent_res,
        off_i, i_pack, ucf, cf16_b, cf_res, (const float4*)item_cf0,
        user, off_u, u_pack, ent_a, (const float4*)all_embed, usr_b);
    // 6) ucf1 (from cf1) + ent-half loss
    fused_u1_loss<<<UCFB + LOSSB, 256, 0, stream>>>(
        off_u, u_pack, cf16_b, ucf, pos_item, neg_item,
        (const half4_t*)usr_b, (const half4_t*)ent_res, dpe, l1pe);
    // 7) item1 (final cf_res)
    item_h1<<<ITEMB, 256, 0, stream>>>(off_i, i_pack, ucf, cf_res,
                                       (const float4*)item_cf0);
    // 8) cf-half loss + combine
    loss_cf_kernel<<<LOSSB, 256, 0, stream>>>(pos_item, neg_item,
                                              (const half4_t*)usr_b, (const half4_t*)cf_res,
                                              dpe, l1pe, l1p);
    // 9) final reduction
    finalize_kernel<<<1, 1024, 0, stream>>>(l1p, l2blk, out);
}

// Round 6
// 348.784 us; speedup vs baseline: 1.1026x; 1.1026x over previous
//
#include <hip/hip_runtime.h>
#include <math.h>

#define N_USERS    100000
#define N_ITEMS    50000
#define N_ENTITIES 200000
#define N_REL      20
#define EMB        64
#define HOPS       2
#define MARGIN_CCL 0.8f
#define NUM_NEG    64
#define ANGLE_W    0.1f
#define ANGLE_DROP 0.5f
#define N_EDGES    1000000
#define NNZ        1000000
#define N_TRIPLETS 200000
#define BATCH      4096
#define EPSF       1e-6f

#define TILE1 2048
#define NBUCK 196
#define ACAP  8192
#define HBLK  ((N_EDGES + TILE1 - 1) / TILE1)   // 489
#define P1B   (3 * HBLK)                     // 1467
#define KGB   (N_ENTITIES / 32)              // 6250
#define UCFB  (N_USERS / 32)                 // 3125
#define ITEMB ((N_ITEMS + 31) / 32)          // 1563
#define UBB   (BATCH / 32)                   // 128
#define ANGB  (N_TRIPLETS / 32)              // 6250
#define LOSSB (BATCH / 4)                    // 1024
#define CONVE (N_ENTITIES * 16 / 256)        // 12500
#define CONVI (N_ITEMS * 16 / 256)           // 3125

typedef _Float16 half4_t __attribute__((ext_vector_type(4)));
typedef _Float16 half8_t __attribute__((ext_vector_type(8)));
typedef float float8_t __attribute__((ext_vector_type(8)));

__device__ inline float4 h2f(half4_t h) {
    return make_float4((float)h.x, (float)h.y, (float)h.z, (float)h.w);
}
__device__ inline half4_t f2h(float4 f) {
    half4_t h; h.x = (_Float16)f.x; h.y = (_Float16)f.y;
    h.z = (_Float16)f.z; h.w = (_Float16)f.w; return h;
}
__device__ inline float8_t h8_to_f8(half8_t h) { return __builtin_convertvector(h, float8_t); }
__device__ inline half8_t f8_to_h8(float8_t f) { return __builtin_convertvector(f, half8_t); }
__device__ inline half8_t h8_zero() {
    half8_t z;
    #pragma unroll
    for (int i = 0; i < 8; ++i) z[i] = (_Float16)0.0f;
    return z;
}
__device__ inline float sum_sq8(float8_t f) {
    float s = 0.f;
    #pragma unroll
    for (int i = 0; i < 8; ++i) s += f[i] * f[i];
    return s;
}
__device__ inline float dot8(float8_t a, float8_t b) {
    float s = 0.f;
    #pragma unroll
    for (int i = 0; i < 8; ++i) s += a[i] * b[i];
    return s;
}
__device__ inline float8_t f8_from2(float4 lo, float4 hi) {
    float8_t f;
    f[0] = lo.x; f[1] = lo.y; f[2] = lo.z; f[3] = lo.w;
    f[4] = hi.x; f[5] = hi.y; f[6] = hi.z; f[7] = hi.w;
    return f;
}
__device__ inline float grp_red8(float v) {
    v += __shfl_xor(v, 1, 64); v += __shfl_xor(v, 2, 64); v += __shfl_xor(v, 4, 64);
    return v;
}
__device__ inline float dot4(float4 a, float4 b) {
    return a.x * b.x + a.y * b.y + a.z * b.z + a.w * b.w;
}
__device__ inline float grp_red16(float v) {
    v += __shfl_xor(v, 1, 64); v += __shfl_xor(v, 2, 64);
    v += __shfl_xor(v, 4, 64); v += __shfl_xor(v, 8, 64);
    return v;
}
__device__ inline float cross_grp_scalar(float v) {
    v += __shfl_xor(v, 16, 64); v += __shfl_xor(v, 32, 64);
    return v;
}
// val is multiplied as fp16 by all consumers; converting at pack time is
// bit-identical to converting at consume time.
__device__ inline int f32_to_h16bits(float v) {
    _Float16 h = (_Float16)v;
    return (int)__builtin_bit_cast(unsigned short, h);
}
__device__ inline _Float16 h16_from_bits(int b) {
    return __builtin_bit_cast(_Float16, (unsigned short)(b & 0xFFFF));
}

// fp16 angle body: 8-lane groups, 32 triplets/block
__device__ inline void angle_body(int ablk, int t, const half8_t* __restrict__ ent_h,
                                  const int* __restrict__ th, const int* __restrict__ tt,
                                  float* sb, float* __restrict__ l2blk) {
    int o = t & 7;
    int grp = t >> 3;
    int trip = ablk * 32 + grp;
    int h = th[trip], t2 = tt[trip];
    float8_t hv = h8_to_f8(ent_h[h * 8 + o]);
    float8_t tv = h8_to_f8(ent_h[t2 * 8 + o]);
    hv *= ANGLE_DROP;
    tv *= ANGLE_DROP;
    float8_t dv = hv - tv;
    float s_hh = grp_red8(sum_sq8(hv));
    float s_tt = grp_red8(sum_sq8(tv));
    float s_ht = grp_red8(dot8(hv, tv));
    float s_dd = grp_red8(sum_sq8(dv));
    if (o == 0) {
        float nu = sqrtf(s_hh);
        float ed = sqrtf(s_dd);
        float sqnu = fminf(fmaxf(s_hh, 0.0f), 1.0f - EPSF);
        float ha_arg = fminf(fmaxf(0.1f * (1.0f - sqnu) / sqrtf(sqnu), -1.0f + EPSF), 1.0f - EPSF);
        float half_ap = asinf(ha_arg);
        float num = s_ht * (1.0f + s_hh) - s_hh * (1.0f + s_tt);
        float den = nu * ed * sqrtf(fmaxf(1.0f + s_tt * s_hh - 2.0f * s_ht, EPSF)) + EPSF;
        float ang = acosf(fminf(fmaxf(num / den, -1.0f + EPSF), 1.0f - EPSF));
        sb[grp] = fmaxf(ang - half_ap, 0.0f);
    }
    __syncthreads();
    if (t == 0) {
        float tot = 0.f;
        #pragma unroll
        for (int i = 0; i < 32; ++i) tot += sb[i];
        l2blk[ablk] = tot;
    }
}

// -------------- phase 1: bucket-grouped placement (+ fp32->fp16 conversions) -----------
// relative cursors (memset to 0 by host-side hipMemsetAsync); arena base = bucket*ACAP
// Staged (LDS) placement for coalesced global writes — R5's direct-write doubled
// WRITE_SIZE (partial-line scatter). Keys+payloads are REGISTER-CACHED between the
// histogram pass and the placement pass: pass 2 is pure LDS (atomic + store), no
// global-load latency in its chain. Staging semantics bit-identical to the R4 kernel.
__global__ void __launch_bounds__(256) phase1_sort(
        const int* __restrict__ head, const int* __restrict__ tail,
        const int* __restrict__ etype, const int* __restrict__ rows,
        const int* __restrict__ cols, const float* __restrict__ vals,
        int* __restrict__ bcur_e, int* __restrict__ bcur_u, int* __restrict__ bcur_i,
        int* __restrict__ keys_ping, int* __restrict__ kg_ping,
        int2* __restrict__ u_ping, int2* __restrict__ i_ping,
        const float4* __restrict__ ent0, const float4* __restrict__ cf0,
        half4_t* __restrict__ ent_a4, half4_t* __restrict__ cf16a4) {
    __shared__ int2 pay_st[TILE1];          // 16 KB; edges alias: key_st / ps halves
    __shared__ int lhist[256], lstart[256], lcur[256];
    __shared__ int wsum[4], wpre[4];
    int* gbase = lhist;                     // safe: own-slot hist read precedes, 2 barriers apart
    int bx = blockIdx.x, t = threadIdx.x;
    if (bx >= P1B) {
        // fp32->fp16 table conversions (streaming; overlap the latency-bound sort)
        int cb = bx - P1B;
        if (cb < CONVE) { int i = cb * 256 + t; ent_a4[i] = f2h(ent0[i]); }
        else            { int i = (cb - CONVE) * 256 + t; cf16a4[i] = f2h(cf0[i]); }
        return;
    }
    int seg = bx / HBLK;
    int tb  = bx % HBLK;
    int tstart = tb * TILE1;
    int valid = min(TILE1, N_EDGES - tstart);
    const int* karr = (seg == 0) ? head : (seg == 1) ? rows : cols;
    int shift = (seg == 0) ? 10 : (seg == 1) ? 9 : 8;
    int* bcur = (seg == 0) ? bcur_e : (seg == 1) ? bcur_u : bcur_i;
    lhist[t] = 0;
    __syncthreads();
    // pass 1: load keys + payloads into registers, build histogram
    int kreg[8], pxr[8], pyr[8];
    #pragma unroll
    for (int j = 0; j < 8; ++j) {
        int i = t + j * 256;
        if (i < valid) {
            int k = karr[tstart + i];
            kreg[j] = k;
            if (seg == 0) {
                pxr[j] = tail[tstart + i] | ((etype[tstart + i] - 1) << 18);
            } else {
                int px;
                if (seg == 1) px = cols[tstart + i] | ((k & 511) << 16);
                else          px = rows[tstart + i] | ((k & 255) << 17);
                pxr[j] = px;
                pyr[j] = f32_to_h16bits(vals[tstart + i]) | ((k >> shift) << 16);
            }
            atomicAdd(&lhist[k >> shift], 1);
        }
    }
    __syncthreads();
    int v = lhist[t];                        // own slot; last read of hist values
    int lane = t & 63, wv = t >> 6;
    int sc = v;
    #pragma unroll
    for (int d = 1; d < 64; d <<= 1) {
        int x = __shfl_up(sc, d, 64);
        if (lane >= d) sc += x;
    }
    if (lane == 63) wsum[wv] = sc;
    __syncthreads();
    if (t == 0) {
        int a = 0;
        #pragma unroll
        for (int i = 0; i < 4; ++i) { wpre[i] = a; a += wsum[i]; }
    }
    __syncthreads();
    int excl = sc + wpre[wv] - v;
    lstart[t] = excl;
    lcur[t] = excl;
    gbase[t] = t * ACAP + atomicAdd(&bcur[t], v);   // overwrites lhist[t] (hist dead)
    __syncthreads();
    if (seg == 0) {
        int* key_st = (int*)pay_st;
        int* ps = key_st + TILE1;
        #pragma unroll
        for (int j = 0; j < 8; ++j) {
            int i = t + j * 256;
            if (i < valid) {
                int sp = atomicAdd(&lcur[kreg[j] >> 10], 1);
                key_st[sp] = kreg[j];
                ps[sp] = pxr[j];
            }
        }
        __syncthreads();
        for (int j = t; j < valid; j += 256) {
            int k = key_st[j];
            int b = k >> 10;
            int pos = gbase[b] + (j - lstart[b]);
            keys_ping[pos] = k;
            kg_ping[pos] = ps[j];
        }
    } else {
        int2* pay = (seg == 1) ? u_ping : i_ping;
        #pragma unroll
        for (int j = 0; j < 8; ++j) {
            int i = t + j * 256;
            if (i < valid) {
                int sp = atomicAdd(&lcur[kreg[j] >> shift], 1);
                pay_st[sp] = make_int2(pxr[j], pyr[j]);
            }
        }
        __syncthreads();
        for (int j = t; j < valid; j += 256) {
            int2 p = pay_st[j];
            int bb = (p.y >> 16) & 0xFF;     // bucket id carried in payload — no search
            int pos = gbase[bb] + (j - lstart[bb]);
            pay[pos] = p;
        }
    }
}

// ------------- phase 2: row offsets + ping->pong scatter (+ angle overlap) -------------
__global__ void __launch_bounds__(256) phase2_angle(
        const int* __restrict__ bcur_e, const int* __restrict__ keys_ping,
        const int* __restrict__ kg_ping, int* __restrict__ kg_pack, int* __restrict__ off_e,
        const int* __restrict__ bcur_u, const int2* __restrict__ u_ping,
        int2* __restrict__ u_pack, int* __restrict__ off_u,
        const int* __restrict__ bcur_i, const int2* __restrict__ i_ping,
        int2* __restrict__ i_pack, int* __restrict__ off_i,
        const half8_t* __restrict__ ent_a, const int* __restrict__ th,
        const int* __restrict__ tt, float* __restrict__ l2blk) {
    __shared__ int hist[1024];
    __shared__ int wsum[4], wpre[4];
    __shared__ float sb[32];
    int t = threadIdx.x;
    if (blockIdx.x >= 3 * NBUCK) {
        angle_body(blockIdx.x - 3 * NBUCK, t, ent_a, th, tt, sb, l2blk);
        return;
    }
    int seg = blockIdx.x / NBUCK;
    int b   = blockIdx.x % NBUCK;
    int bins  = (seg == 0) ? 1024 : (seg == 1) ? 512 : 256;
    int shift = (seg == 0) ? 10 : (seg == 1) ? 9 : 8;
    int n_rows = (seg == 0) ? N_ENTITIES : (seg == 1) ? N_USERS : N_ITEMS;
    const int* bcur = (seg == 0) ? bcur_e : (seg == 1) ? bcur_u : bcur_i;
    int* off = (seg == 0) ? off_e : (seg == 1) ? off_u : off_i;
    int rs = b << shift;
    int re = min(rs + bins, n_rows);
    int nr = re - rs;
    int base = b * ACAP;
    int len = bcur[b];                       // relative cursor = count
    for (int r = t; r < bins; r += 256) hist[r] = 0;
    __syncthreads();
    if (seg == 0) {
        for (int j = t; j < len; j += 256) atomicAdd(&hist[keys_ping[base + j] - rs], 1);
    } else if (seg == 1) {
        for (int j = t; j < len; j += 256) atomicAdd(&hist[(u_ping[base + j].x >> 16) & 511], 1);
    } else {
        for (int j = t; j < len; j += 256) atomicAdd(&hist[(i_ping[base + j].x >> 17) & 255], 1);
    }
    __syncthreads();
    int own = bins >> 8;
    int c[4]; int tot = 0;
    #pragma unroll
    for (int i = 0; i < 4; ++i) { c[i] = (i < own) ? hist[t * own + i] : 0; tot += c[i]; }
    int lane = t & 63, wv = t >> 6;
    int sc = tot;
    #pragma unroll
    for (int d = 1; d < 64; d <<= 1) {
        int x = __shfl_up(sc, d, 64);
        if (lane >= d) sc += x;
    }
    if (lane == 63) wsum[wv] = sc;
    __syncthreads();
    if (t == 0) {
        int a = 0;
        #pragma unroll
        for (int i = 0; i < 4; ++i) { wpre[i] = a; a += wsum[i]; }
    }
    __syncthreads();
    int run = sc + wpre[wv] - tot;
    #pragma unroll
    for (int i = 0; i < 4; ++i) { if (i < own) { hist[t * own + i] = run; run += c[i]; } }
    __syncthreads();
    for (int r = t; r < nr; r += 256) off[rs + b + r] = base + hist[r];
    if (t == 0) off[rs + b + nr] = base + len;
    __syncthreads();
    if (seg == 0) {
        for (int j = t; j < len; j += 256) {
            int k = keys_ping[base + j];
            int slot = atomicAdd(&hist[k - rs], 1);
            kg_pack[base + slot] = kg_ping[base + j];
        }
    } else if (seg == 1) {
        for (int j = t; j < len; j += 256) {
            int2 p = u_ping[base + j];
            int slot = atomicAdd(&hist[(p.x >> 16) & 511], 1);
            u_pack[base + slot] = p;
        }
    } else {
        for (int j = t; j < len; j += 256) {
            int2 p = i_ping[base + j];
            int slot = atomicAdd(&hist[(p.x >> 17) & 255], 1);
            i_pack[base + slot] = p;
        }
    }
}

// ------------------------------ hop bodies ------------------------------
// 4-edge unroll: gathers issued together for MLP; fp16 accumulation order
// (strictly ascending k, one add per edge) identical to the 2-unroll version.
__device__ inline void kg0_body(int bid, int t, const int* __restrict__ off,
                                const int* __restrict__ pack, half8_t* srel,
                                const float* __restrict__ relw,
                                const half8_t* __restrict__ src, half8_t* __restrict__ dst,
                                half8_t* __restrict__ res, const float4* __restrict__ res_init) {
    if (t < (N_REL - 1) * 8) {
        int rel = t >> 3, o = t & 7;
        const float4* r4 = (const float4*)relw;
        srel[rel * 9 + o] = f8_to_h8(f8_from2(r4[rel * 16 + o * 2], r4[rel * 16 + o * 2 + 1]));
    }
    __syncthreads();
    int row = bid * 32 + (t >> 3);
    int o = t & 7;
    int idx = row + (row >> 10);
    int s = off[idx], e = off[idx + 1];
    half8_t acc = h8_zero();
    int k = s;
    for (; k + 4 <= e; k += 4) {
        int p0 = pack[k], p1 = pack[k + 1], p2 = pack[k + 2], p3 = pack[k + 3];
        half8_t a0 = src[(p0 & 0x3FFFF) * 8 + o];
        half8_t a1 = src[(p1 & 0x3FFFF) * 8 + o];
        half8_t a2 = src[(p2 & 0x3FFFF) * 8 + o];
        half8_t a3 = src[(p3 & 0x3FFFF) * 8 + o];
        acc += a0 * srel[(p0 >> 18) * 9 + o];
        acc += a1 * srel[(p1 >> 18) * 9 + o];
        acc += a2 * srel[(p2 >> 18) * 9 + o];
        acc += a3 * srel[(p3 >> 18) * 9 + o];
    }
    for (; k < e; ++k) {
        int p0 = pack[k];
        acc += src[(p0 & 0x3FFFF) * 8 + o] * srel[(p0 >> 18) * 9 + o];
    }
    float8_t f = h8_to_f8(acc);
    f *= 1.0f / fmaxf((float)(e - s), 1.0f);
    float ss = grp_red8(sum_sq8(f));
    f *= 1.0f / fmaxf(sqrtf(ss), 1e-12f);
    dst[row * 8 + o] = f8_to_h8(f);
    if (row < N_ITEMS) {
        float8_t rr = f8_from2(res_init[row * 16 + o * 2], res_init[row * 16 + o * 2 + 1]);
        rr += f;
        res[row * 8 + o] = f8_to_h8(rr);
    }
}

__device__ inline void kg2_body(int bid, int t, const int* __restrict__ off,
                                const int* __restrict__ pack, half8_t* srel,
                                const float* __restrict__ relw,
                                const half8_t* __restrict__ src, half8_t* __restrict__ res) {
    if (t < (N_REL - 1) * 8) {
        int rel = t >> 3, o = t & 7;
        const float4* r4 = (const float4*)relw;
        srel[rel * 9 + o] = f8_to_h8(f8_from2(r4[rel * 16 + o * 2], r4[rel * 16 + o * 2 + 1]));
    }
    __syncthreads();
    int row = bid * 32 + (t >> 3);
    if (row >= N_ITEMS) return;
    int o = t & 7;
    int idx = row + (row >> 10);
    int s = off[idx], e = off[idx + 1];
    half8_t acc = h8_zero();
    int k = s;
    for (; k + 4 <= e; k += 4) {
        int p0 = pack[k], p1 = pack[k + 1], p2 = pack[k + 2], p3 = pack[k + 3];
        half8_t a0 = src[(p0 & 0x3FFFF) * 8 + o];
        half8_t a1 = src[(p1 & 0x3FFFF) * 8 + o];
        half8_t a2 = src[(p2 & 0x3FFFF) * 8 + o];
        half8_t a3 = src[(p3 & 0x3FFFF) * 8 + o];
        acc += a0 * srel[(p0 >> 18) * 9 + o];
        acc += a1 * srel[(p1 >> 18) * 9 + o];
        acc += a2 * srel[(p2 >> 18) * 9 + o];
        acc += a3 * srel[(p3 >> 18) * 9 + o];
    }
    for (; k < e; ++k) {
        int p0 = pack[k];
        acc += src[(p0 & 0x3FFFF) * 8 + o] * srel[(p0 >> 18) * 9 + o];
    }
    float8_t f = h8_to_f8(acc);
    f *= 1.0f / fmaxf((float)(e - s), 1.0f);
    float ss = grp_red8(sum_sq8(f));
    f *= 1.0f / fmaxf(sqrtf(ss), 1e-12f);
    float8_t rr = h8_to_f8(res[row * 8 + o]);
    rr += f;
    float s2 = grp_red8(sum_sq8(rr));
    rr *= 1.0f / fmaxf(sqrtf(s2), 1e-12f);
    res[row * 8 + o] = f8_to_h8(rr);
}

__device__ inline void ucf_body(int bid, int t, const int* __restrict__ off,
                                const int2* __restrict__ u_pack,
                                const half8_t* __restrict__ cf16,
                                half8_t* __restrict__ ucf) {
    int row = bid * 32 + (t >> 3);
    int o = t & 7;
    int idx = row + (row >> 9);
    int s = off[idx], e = off[idx + 1];
    half8_t acc = h8_zero();
    int k = s;
    for (; k + 4 <= e; k += 4) {
        int2 p0 = u_pack[k], p1 = u_pack[k + 1], p2 = u_pack[k + 2], p3 = u_pack[k + 3];
        half8_t c0 = cf16[(p0.x & 0xFFFF) * 8 + o];
        half8_t c1 = cf16[(p1.x & 0xFFFF) * 8 + o];
        half8_t c2 = cf16[(p2.x & 0xFFFF) * 8 + o];
        half8_t c3 = cf16[(p3.x & 0xFFFF) * 8 + o];
        acc += c0 * h16_from_bits(p0.y);
        acc += c1 * h16_from_bits(p1.y);
        acc += c2 * h16_from_bits(p2.y);
        acc += c3 * h16_from_bits(p3.y);
    }
    for (; k < e; ++k) {
        int2 p0 = u_pack[k];
        acc += cf16[(p0.x & 0xFFFF) * 8 + o] * h16_from_bits(p0.y);
    }
    ucf[row * 8 + o] = acc;
}

__device__ inline void ubatch_body(int bid, int t, const int* __restrict__ user,
                                   const int* __restrict__ off,
                                   const int2* __restrict__ u_pack,
                                   const half8_t* __restrict__ ent_a,
                                   const half8_t* __restrict__ ent_b,
                                   const float4* __restrict__ usr0f,
                                   half8_t* __restrict__ usr_b) {
    int g = t >> 3, o = t & 7;
    int b = bid * 32 + g;
    int uid = user[b];
    int idx = uid + (uid >> 9);
    int s = off[idx], e = off[idx + 1];
    half8_t acc1 = h8_zero(), acc2 = h8_zero();
    int k = s;
    for (; k + 4 <= e; k += 4) {
        int2 p0 = u_pack[k], p1 = u_pack[k + 1], p2 = u_pack[k + 2], p3 = u_pack[k + 3];
        int c0 = (p0.x & 0xFFFF) * 8 + o;
        int c1 = (p1.x & 0xFFFF) * 8 + o;
        int c2 = (p2.x & 0xFFFF) * 8 + o;
        int c3 = (p3.x & 0xFFFF) * 8 + o;
        half8_t ea0 = ent_a[c0], eb0 = ent_b[c0];
        half8_t ea1 = ent_a[c1], eb1 = ent_b[c1];
        half8_t ea2 = ent_a[c2], eb2 = ent_b[c2];
        half8_t ea3 = ent_a[c3], eb3 = ent_b[c3];
        _Float16 v0 = h16_from_bits(p0.y);
        _Float16 v1 = h16_from_bits(p1.y);
        _Float16 v2 = h16_from_bits(p2.y);
        _Float16 v3 = h16_from_bits(p3.y);
        acc1 += ea0 * v0; acc2 += eb0 * v0;
        acc1 += ea1 * v1; acc2 += eb1 * v1;
        acc1 += ea2 * v2; acc2 += eb2 * v2;
        acc1 += ea3 * v3; acc2 += eb3 * v3;
    }
    for (; k < e; ++k) {
        int2 p0 = u_pack[k];
        int c0 = (p0.x & 0xFFFF) * 8 + o;
        _Float16 v0 = h16_from_bits(p0.y);
        acc1 += ent_a[c0] * v0;
        acc2 += ent_b[c0] * v0;
    }
    float8_t f1 = h8_to_f8(acc1);
    float ss1 = grp_red8(sum_sq8(f1));
    f1 *= 1.0f / fmaxf(sqrtf(ss1), 1e-12f);
    float8_t u0 = f8_from2(usr0f[uid * 16 + o * 2], usr0f[uid * 16 + o * 2 + 1]);
    float8_t r1 = h8_to_f8(f8_to_h8(u0 + f1));   // fp16 round-trip (matches hop-1 store)
    float8_t f2 = h8_to_f8(acc2);
    float ss2 = grp_red8(sum_sq8(f2));
    f2 *= 1.0f / fmaxf(sqrtf(ss2), 1e-12f);
    float8_t r = r1 + f2;
    float s3 = grp_red8(sum_sq8(r));
    r *= 1.0f / fmaxf(sqrtf(s3), 1e-12f);
    usr_b[b * 8 + o] = f8_to_h8(r);
}

__device__ inline void item_body(int bid, int t, const int* __restrict__ off,
                                 const int2* __restrict__ i_pack,
                                 const half8_t* __restrict__ ucf,
                                 half8_t* __restrict__ cf_nxt, half8_t* __restrict__ res,
                                 const float4* __restrict__ res_init, int first, int last) {
    int row = bid * 32 + (t >> 3);
    int o = t & 7;
    if (row >= N_ITEMS) return;
    int idx = row + (row >> 8);
    int s = off[idx], e = off[idx + 1];
    half8_t acc = h8_zero();
    int k = s;
    for (; k + 4 <= e; k += 4) {
        int2 p0 = i_pack[k], p1 = i_pack[k + 1], p2 = i_pack[k + 2], p3 = i_pack[k + 3];
        half8_t c0 = ucf[(p0.x & 0x1FFFF) * 8 + o];
        half8_t c1 = ucf[(p1.x & 0x1FFFF) * 8 + o];
        half8_t c2 = ucf[(p2.x & 0x1FFFF) * 8 + o];
        half8_t c3 = ucf[(p3.x & 0x1FFFF) * 8 + o];
        acc += c0 * h16_from_bits(p0.y);
        acc += c1 * h16_from_bits(p1.y);
        acc += c2 * h16_from_bits(p2.y);
        acc += c3 * h16_from_bits(p3.y);
    }
    for (; k < e; ++k) {
        int2 p0 = i_pack[k];
        acc += ucf[(p0.x & 0x1FFFF) * 8 + o] * h16_from_bits(p0.y);
    }
    float8_t f = h8_to_f8(acc);
    float ss = grp_red8(sum_sq8(f));
    f *= 1.0f / fmaxf(sqrtf(ss), 1e-12f);
    if (!last) cf_nxt[row * 8 + o] = f8_to_h8(f);
    float8_t rr;
    if (first) rr = f8_from2(res_init[row * 16 + o * 2], res_init[row * 16 + o * 2 + 1]);
    else       rr = h8_to_f8(res[row * 8 + o]);
    rr += f;
    if (last) {
        float s2 = grp_red8(sum_sq8(rr));
        rr *= 1.0f / fmaxf(sqrtf(s2), 1e-12f);
    }
    res[row * 8 + o] = f8_to_h8(rr);
}

// loss halves — 16 negatives per round for MLP; accumulation order unchanged
__device__ inline void loss_ent_body(int b, int t,
                                     const int* __restrict__ pos, const int* __restrict__ neg,
                                     const half4_t* __restrict__ usrb4,
                                     const half4_t* __restrict__ ent4,
                                     float* __restrict__ dpe, float* __restrict__ l1pe) {
    int lane = t & 63;
    int g = lane >> 4, q = lane & 15;
    int pid = pos[b];
    float4 u = h2f(usrb4[b * 16 + q]);
    float4 p = h2f(ent4[pid * 16 + q]);
    float dpe_v = grp_red16(dot4(u, p));
    float sum_n = 0.f, cnt_n = 0.f;
    const int* nb = neg + b * NUM_NEG;
    for (int j = 0; j < NUM_NEG; j += 16) {
        int n0 = nb[j + g], n1 = nb[j + 4 + g], n2 = nb[j + 8 + g], n3 = nb[j + 12 + g];
        float4 e0 = h2f(ent4[n0 * 16 + q]);
        float4 e1 = h2f(ent4[n1 * 16 + q]);
        float4 e2 = h2f(ent4[n2 * 16 + q]);
        float4 e3 = h2f(ent4[n3 * 16 + q]);
        float dn0 = grp_red16(dot4(u, e0));
        float dn1 = grp_red16(dot4(u, e1));
        float dn2 = grp_red16(dot4(u, e2));
        float dn3 = grp_red16(dot4(u, e3));
        float s0 = fmaxf(dn0 - MARGIN_CCL, 0.f); sum_n += s0; if (s0 > 0.f) cnt_n += 1.f;
        float s1 = fmaxf(dn1 - MARGIN_CCL, 0.f); sum_n += s1; if (s1 > 0.f) cnt_n += 1.f;
        float s2 = fmaxf(dn2 - MARGIN_CCL, 0.f); sum_n += s2; if (s2 > 0.f) cnt_n += 1.f;
        float s3 = fmaxf(dn3 - MARGIN_CCL, 0.f); sum_n += s3; if (s3 > 0.f) cnt_n += 1.f;
    }
    sum_n = cross_grp_scalar(sum_n); cnt_n = cross_grp_scalar(cnt_n);
    if (lane == 0) {
        dpe[b] = dpe_v;
        l1pe[b] = sum_n / (cnt_n + 1e-5f);
    }
}

__global__ void __launch_bounds__(256) loss_cf_kernel(
        const int* __restrict__ pos, const int* __restrict__ neg,
        const half4_t* __restrict__ usrb4, const half4_t* __restrict__ cf4,
        const float* __restrict__ dpe, const float* __restrict__ l1pe,
        float* __restrict__ l1p) {
    int b = blockIdx.x * 4 + (threadIdx.x >> 6);
    int lane = threadIdx.x & 63;
    int g = lane >> 4, q = lane & 15;
    int pid = pos[b];
    float4 u = h2f(usrb4[b * 16 + q]);
    float4 pc = h2f(cf4[pid * 16 + q]);
    float dpc = grp_red16(dot4(u, pc));
    float sum_c = 0.f, cnt_c = 0.f;
    const int* nb = neg + b * NUM_NEG;
    for (int j = 0; j < NUM_NEG; j += 16) {
        int n0 = nb[j + g], n1 = nb[j + 4 + g], n2 = nb[j + 8 + g], n3 = nb[j + 12 + g];
        float4 e0 = h2f(cf4[n0 * 16 + q]);
        float4 e1 = h2f(cf4[n1 * 16 + q]);
        float4 e2 = h2f(cf4[n2 * 16 + q]);
        float4 e3 = h2f(cf4[n3 * 16 + q]);
        float dc0 = grp_red16(dot4(u, e0));
        float dc1 = grp_red16(dot4(u, e1));
        float dc2 = grp_red16(dot4(u, e2));
        float dc3 = grp_red16(dot4(u, e3));
        float t0 = fmaxf(dc0 - MARGIN_CCL, 0.f); sum_c += t0; if (t0 > 0.f) cnt_c += 1.f;
        float t1 = fmaxf(dc1 - MARGIN_CCL, 0.f); sum_c += t1; if (t1 > 0.f) cnt_c += 1.f;
        float t2 = fmaxf(dc2 - MARGIN_CCL, 0.f); sum_c += t2; if (t2 > 0.f) cnt_c += 1.f;
        float t3 = fmaxf(dc3 - MARGIN_CCL, 0.f); sum_c += t3; if (t3 > 0.f) cnt_c += 1.f;
    }
    sum_c = cross_grp_scalar(sum_c); cnt_c = cross_grp_scalar(cnt_c);
    if (lane == 0) {
        float ui_pos = fmaxf(2.0f - dpe[b] - dpc, 0.0f);
        l1p[b] = ui_pos + l1pe[b] + sum_c / (cnt_c + 1e-5f);
    }
}

// --------------------------- fused launches ---------------------------
// kg0 (full) + ucf0 (cf-only, all users)
__global__ void __launch_bounds__(256) fused_h0(
        const int* __restrict__ off_e, const int* __restrict__ kg_pack,
        const float* __restrict__ relw, const half8_t* __restrict__ ent_a,
        half8_t* __restrict__ ent_b, half8_t* __restrict__ ent_res,
        const float4* __restrict__ ent0f,
        const int* __restrict__ off_u, const int2* __restrict__ u_pack,
        const half8_t* __restrict__ cf16_a, half8_t* __restrict__ ucf) {
    __shared__ half8_t srel[(N_REL - 1) * 9];
    int bx = blockIdx.x, t = threadIdx.x;
    if (bx < KGB) {
        kg0_body(bx, t, off_e, kg_pack, srel, relw, ent_a, ent_b, ent_res, ent0f);
    } else {
        ucf_body(bx - KGB, t, off_u, u_pack, cf16_a, ucf);
    }
}

// kg1 (item rows only) + item0 + batch-user embedding
__global__ void __launch_bounds__(256) fused_ik(
        const int* __restrict__ off_e, const int* __restrict__ kg_pack,
        const float* __restrict__ relw, const half8_t* __restrict__ ent_b,
        half8_t* __restrict__ ent_res,
        const int* __restrict__ off_i, const int2* __restrict__ i_pack,
        const half8_t* __restrict__ ucf, half8_t* __restrict__ cf16_b,
        half8_t* __restrict__ cf_res, const float4* __restrict__ cf0f,
        const int* __restrict__ user, const int* __restrict__ off_u,
        const int2* __restrict__ u_pack, const half8_t* __restrict__ ent_a,
        const float4* __restrict__ usr0f, half8_t* __restrict__ usr_b) {
    __shared__ half8_t srel[(N_REL - 1) * 9];
    int bx = blockIdx.x, t = threadIdx.x;
    if (bx < ITEMB) {
        kg2_body(bx, t, off_e, kg_pack, srel, relw, ent_b, ent_res);
    } else if (bx < 2 * ITEMB) {
        item_body(bx - ITEMB, t, off_i, i_pack, ucf, cf16_b, cf_res, cf0f, 1, 0);
    } else {
        ubatch_body(bx - 2 * ITEMB, t, user, off_u, u_pack, ent_a, ent_b, usr0f, usr_b);
    }
}

// ucf hop-1 (from cf1) + ent-half loss
__global__ void __launch_bounds__(256) fused_u1_loss(
        const int* __restrict__ off_u, const int2* __restrict__ u_pack,
        const half8_t* __restrict__ cf16_b, half8_t* __restrict__ ucf,
        const int* __restrict__ pos, const int* __restrict__ neg,
        const half4_t* __restrict__ usrb4, const half4_t* __restrict__ ent4,
        float* __restrict__ dpe, float* __restrict__ l1pe) {
    int bx = blockIdx.x, t = threadIdx.x;
    if (bx < UCFB) {
        ucf_body(bx, t, off_u, u_pack, cf16_b, ucf);
    } else {
        int b = (bx - UCFB) * 4 + (t >> 6);
        loss_ent_body(b, t, pos, neg, usrb4, ent4, dpe, l1pe);
    }
}

__global__ void __launch_bounds__(256) item_h1(
        const int* __restrict__ off_i, const int2* __restrict__ i_pack,
        const half8_t* __restrict__ ucf, half8_t* __restrict__ cf_res,
        const float4* __restrict__ cf0f) {
    item_body(blockIdx.x, threadIdx.x, off_i, i_pack, ucf, (half8_t*)0, cf_res, cf0f, 0, 1);
}

__global__ void finalize_kernel(const float* __restrict__ l1p, const float* __restrict__ l2b,
                                float* __restrict__ out) {
    __shared__ float sb[1024];
    float a1 = 0.f;
    for (int i = threadIdx.x; i < BATCH; i += 1024) a1 += l1p[i];
    float a2 = 0.f;
    for (int i = threadIdx.x; i < ANGB; i += 1024) a2 += l2b[i];
    sb[threadIdx.x] = a1 / (float)BATCH + ANGLE_W * a2 / (float)N_TRIPLETS;
    __syncthreads();
    for (int s = 512; s > 0; s >>= 1) {
        if (threadIdx.x < s) sb[threadIdx.x] += sb[threadIdx.x + s];
        __syncthreads();
    }
    if (threadIdx.x == 0) out[0] = sb[0];
}

extern "C" void kernel_launch(void* const* d_in, const int* in_sizes, int n_in,
                              void* d_out, int out_size, void* d_ws, size_t ws_size,
                              hipStream_t stream) {
    const float* all_embed = (const float*)d_in[0];
    const float* item_cf0  = (const float*)d_in[1];
    const float* relw      = (const float*)d_in[2];
    const float* vals      = (const float*)d_in[3];
    const int* user        = (const int*)d_in[4];
    const int* pos_item    = (const int*)d_in[5];
    const int* neg_item    = (const int*)d_in[6];
    const int* edge_head   = (const int*)d_in[7];
    const int* edge_tail   = edge_head + N_EDGES;
    const int* etype       = (const int*)d_in[8];
    const int* irows       = (const int*)d_in[9];
    const int* icols       = (const int*)d_in[10];
    const int* th          = (const int*)d_in[11];
    const int* tt          = (const int*)d_in[12];
    float* out             = (float*)d_out;

    char* base = (char*)d_ws;
    size_t woff = 0;
    auto alloc = [&](size_t bytes) -> void* {
        void* p = base + woff;
        woff = (woff + bytes + 255) & ~(size_t)255;
        return p;
    };
    const size_t ping_ui = (size_t)NBUCK * ACAP * 8;    // 12,845,056 B
    const size_t ping_kg = (size_t)NBUCK * ACAP * 4;    // 6,422,528 B

    half8_t* ent_a   = (half8_t*)alloc((size_t)N_ENTITIES * EMB * 2);
    // ent_b hosts the u/i ping arenas before fused_h0 writes it (bumped to fit both)
    half8_t* ent_b   = (half8_t*)alloc(2 * ping_ui);
    half8_t* cf16_a  = (half8_t*)alloc((size_t)N_ITEMS * EMB * 2);
    // cf16_b hosts the kg payload ping before fused_ik writes it (bumped)
    half8_t* cf16_b  = (half8_t*)alloc(ping_kg);
    // ucf hosts the kg keys ping before fused_h0 writes it (12.8 MB >= 6.42 MB)
    half8_t* ucf     = (half8_t*)alloc((size_t)N_USERS * EMB * 2);
    half8_t* ent_res = (half8_t*)alloc((size_t)N_ITEMS * EMB * 2);
    half8_t* cf_res  = (half8_t*)alloc((size_t)N_ITEMS * EMB * 2);
    half8_t* usr_b   = (half8_t*)alloc((size_t)BATCH * EMB * 2);
    int2* u_pack     = (int2*)alloc(ping_ui);
    int2* i_pack     = (int2*)alloc(ping_ui);
    int* kg_pack     = (int*)alloc(ping_kg);
    float* l1p       = (float*)alloc((size_t)BATCH * 4);
    float* dpe       = (float*)alloc((size_t)BATCH * 4);
    float* l1pe      = (float*)alloc((size_t)BATCH * 4);
    float* l2blk     = (float*)alloc((size_t)ANGB * 4);
    int* off_e       = (int*)alloc((size_t)(N_ENTITIES + NBUCK + 1) * 4);
    int* off_u       = (int*)alloc((size_t)(N_USERS + NBUCK + 1) * 4);
    int* off_i       = (int*)alloc((size_t)(N_ITEMS + NBUCK + 1) * 4);
    int* bcur_all    = (int*)alloc(3 * 256 * 4);
    int* bcur_e      = bcur_all;
    int* bcur_u      = bcur_all + 256;
    int* bcur_i      = bcur_all + 512;

    // ping aliases (lifetimes: written phase1, read phase2, dead before host write)
    int2* u_ping   = (int2*)ent_b;
    int2* i_ping   = (int2*)((char*)ent_b + ping_ui);
    int* kg_ping   = (int*)cf16_b;
    int* keys_ping = (int*)ucf;

    const float* ent0 = all_embed + (size_t)N_USERS * EMB;

    // 1) zero relative arena cursors (capture-safe async memset)
    hipMemsetAsync(bcur_all, 0, 3 * 256 * 4, stream);
    // 2) phase 1 placement into pings + fp32->fp16 conversions (overlapped)
    phase1_sort<<<P1B + CONVE + CONVI, 256, 0, stream>>>(
        edge_head, edge_tail, etype, irows, icols, vals,
        bcur_e, bcur_u, bcur_i, keys_ping, kg_ping, u_ping, i_ping,
        (const float4*)ent0, (const float4*)item_cf0, (half4_t*)ent_a, (half4_t*)cf16_a);
    // 3) phase 2: row offsets + ping->pong scatter, angle blocks as filler
    phase2_angle<<<3 * NBUCK + ANGB, 256, 0, stream>>>(
        bcur_e, keys_ping, kg_ping, kg_pack, off_e,
        bcur_u, u_ping, u_pack, off_u,
        bcur_i, i_ping, i_pack, off_i,
        (const half8_t*)ent_a, th, tt, l2blk);
    // 4) kg0 (full) + ucf0
    fused_h0<<<KGB + UCFB, 256, 0, stream>>>(
        off_e, kg_pack, relw, ent_a, ent_b, ent_res, (const float4*)ent0,
        off_u, u_pack, cf16_a, ucf);
    // 5) kg1 (items only) + item0 + batch-user embedding
    fused_ik<<<2 * ITEMB + UBB, 256, 0, stream>>>(
        off_e, kg_pack, relw, ent_b, ent_res,
        off_i, i_pack, ucf, cf16_b, cf_res, (const float4*)item_cf0,
        user, off_u, u_pack, ent_a, (const float4*)all_embed, usr_b);
    // 6) ucf1 (from cf1) + ent-half loss
    fused_u1_loss<<<UCFB + LOSSB, 256, 0, stream>>>(
        off_u, u_pack, cf16_b, ucf, pos_item, neg_item,
        (const half4_t*)usr_b, (const half4_t*)ent_res, dpe, l1pe);
    // 7) item1 (final cf_res)
    item_h1<<<ITEMB, 256, 0, stream>>>(off_i, i_pack, ucf, cf_res,
                                       (const float4*)item_cf0);
    // 8) cf-half loss + combine
    loss_cf_kernel<<<LOSSB, 256, 0, stream>>>(pos_item, neg_item,
                                              (const half4_t*)usr_b, (const half4_t*)cf_res,
                                              dpe, l1pe, l1p);
    // 9) final reduction
    finalize_kernel<<<1, 1024, 0, stream>>>(l1p, l2blk, out);
}

// Round 7
// 343.844 us; speedup vs baseline: 1.1185x; 1.0144x over previous
//
#include <hip/hip_runtime.h>
#include <math.h>

#define N_USERS    100000
#define N_ITEMS    50000
#define N_ENTITIES 200000
#define N_REL      20
#define EMB        64
#define HOPS       2
#define MARGIN_CCL 0.8f
#define NUM_NEG    64
#define ANGLE_W    0.1f
#define ANGLE_DROP 0.5f
#define N_EDGES    1000000
#define NNZ        1000000
#define N_TRIPLETS 200000
#define BATCH      4096
#define EPSF       1e-6f

#define TILE1 2048
#define NBUCK 196
#define ACAP  8192
#define HBLK  ((N_EDGES + TILE1 - 1) / TILE1)   // 489
#define P1B   (3 * HBLK)                     // 1467
#define KGB   (N_ENTITIES / 32)              // 6250
#define UCFB  (N_USERS / 32)                 // 3125
#define ITEMB ((N_ITEMS + 31) / 32)          // 1563
#define UBB   (BATCH / 32)                   // 128
#define ANGB  (N_TRIPLETS / 32)              // 6250
#define LOSSB (BATCH / 4)                    // 1024
#define CONV4E (N_ENTITIES * 16 / 1024)      // 3125
#define CONV4I ((N_ITEMS * 16 + 1023) / 1024) // 782

typedef _Float16 half4_t __attribute__((ext_vector_type(4)));
typedef _Float16 half8_t __attribute__((ext_vector_type(8)));
typedef float float8_t __attribute__((ext_vector_type(8)));

__device__ inline float4 h2f(half4_t h) {
    return make_float4((float)h.x, (float)h.y, (float)h.z, (float)h.w);
}
__device__ inline half4_t f2h(float4 f) {
    half4_t h; h.x = (_Float16)f.x; h.y = (_Float16)f.y;
    h.z = (_Float16)f.z; h.w = (_Float16)f.w; return h;
}
__device__ inline float8_t h8_to_f8(half8_t h) { return __builtin_convertvector(h, float8_t); }
__device__ inline half8_t f8_to_h8(float8_t f) { return __builtin_convertvector(f, half8_t); }
__device__ inline half8_t h8_zero() {
    half8_t z;
    #pragma unroll
    for (int i = 0; i < 8; ++i) z[i] = (_Float16)0.0f;
    return z;
}
__device__ inline float sum_sq8(float8_t f) {
    float s = 0.f;
    #pragma unroll
    for (int i = 0; i < 8; ++i) s += f[i] * f[i];
    return s;
}
__device__ inline float dot8(float8_t a, float8_t b) {
    float s = 0.f;
    #pragma unroll
    for (int i = 0; i < 8; ++i) s += a[i] * b[i];
    return s;
}
__device__ inline float8_t f8_from2(float4 lo, float4 hi) {
    float8_t f;
    f[0] = lo.x; f[1] = lo.y; f[2] = lo.z; f[3] = lo.w;
    f[4] = hi.x; f[5] = hi.y; f[6] = hi.z; f[7] = hi.w;
    return f;
}
__device__ inline float grp_red8(float v) {
    v += __shfl_xor(v, 1, 64); v += __shfl_xor(v, 2, 64); v += __shfl_xor(v, 4, 64);
    return v;
}
__device__ inline float dot4(float4 a, float4 b) {
    return a.x * b.x + a.y * b.y + a.z * b.z + a.w * b.w;
}
__device__ inline float grp_red16(float v) {
    v += __shfl_xor(v, 1, 64); v += __shfl_xor(v, 2, 64);
    v += __shfl_xor(v, 4, 64); v += __shfl_xor(v, 8, 64);
    return v;
}
__device__ inline float cross_grp_scalar(float v) {
    v += __shfl_xor(v, 16, 64); v += __shfl_xor(v, 32, 64);
    return v;
}
// val is multiplied as fp16 by all consumers; converting at pack time is
// bit-identical to converting at consume time.
__device__ inline int f32_to_h16bits(float v) {
    _Float16 h = (_Float16)v;
    return (int)__builtin_bit_cast(unsigned short, h);
}
__device__ inline _Float16 h16_from_bits(int b) {
    return __builtin_bit_cast(_Float16, (unsigned short)(b & 0xFFFF));
}

// fp16 angle body: 8-lane groups, 32 triplets/block
__device__ inline void angle_body(int ablk, int t, const half8_t* __restrict__ ent_h,
                                  const int* __restrict__ th, const int* __restrict__ tt,
                                  float* sb, float* __restrict__ l2blk) {
    int o = t & 7;
    int grp = t >> 3;
    int trip = ablk * 32 + grp;
    int h = th[trip], t2 = tt[trip];
    float8_t hv = h8_to_f8(ent_h[h * 8 + o]);
    float8_t tv = h8_to_f8(ent_h[t2 * 8 + o]);
    hv *= ANGLE_DROP;
    tv *= ANGLE_DROP;
    float8_t dv = hv - tv;
    float s_hh = grp_red8(sum_sq8(hv));
    float s_tt = grp_red8(sum_sq8(tv));
    float s_ht = grp_red8(dot8(hv, tv));
    float s_dd = grp_red8(sum_sq8(dv));
    if (o == 0) {
        float nu = sqrtf(s_hh);
        float ed = sqrtf(s_dd);
        float sqnu = fminf(fmaxf(s_hh, 0.0f), 1.0f - EPSF);
        float ha_arg = fminf(fmaxf(0.1f * (1.0f - sqnu) / sqrtf(sqnu), -1.0f + EPSF), 1.0f - EPSF);
        float half_ap = asinf(ha_arg);
        float num = s_ht * (1.0f + s_hh) - s_hh * (1.0f + s_tt);
        float den = nu * ed * sqrtf(fmaxf(1.0f + s_tt * s_hh - 2.0f * s_ht, EPSF)) + EPSF;
        float ang = acosf(fminf(fmaxf(num / den, -1.0f + EPSF), 1.0f - EPSF));
        sb[grp] = fmaxf(ang - half_ap, 0.0f);
    }
    __syncthreads();
    if (t == 0) {
        float tot = 0.f;
        #pragma unroll
        for (int i = 0; i < 32; ++i) tot += sb[i];
        l2blk[ablk] = tot;
    }
}

// -------------- phase 1: bucket-grouped placement (+ fp32->fp16 conversions) -----------
// relative cursors (memset to 0 by host-side hipMemsetAsync); arena base = bucket*ACAP
// Staged (LDS) placement for coalesced global writes. Conversions: 4 float4s per
// thread (4x fewer, fatter blocks -> conv tail is 4 loads in flight, not 1).
__global__ void __launch_bounds__(256) phase1_sort(
        const int* __restrict__ head, const int* __restrict__ tail,
        const int* __restrict__ etype, const int* __restrict__ rows,
        const int* __restrict__ cols, const float* __restrict__ vals,
        int* __restrict__ bcur_e, int* __restrict__ bcur_u, int* __restrict__ bcur_i,
        int* __restrict__ keys_ping, int* __restrict__ kg_ping,
        int2* __restrict__ u_ping, int2* __restrict__ i_ping,
        const float4* __restrict__ ent0, const float4* __restrict__ cf0,
        half4_t* __restrict__ ent_a4, half4_t* __restrict__ cf16a4) {
    __shared__ int2 pay_st[TILE1];          // 16 KB; edges alias: key_st / ps halves
    __shared__ int lhist[256], lstart[256], lcur[256];
    __shared__ int wsum[4], wpre[4];
    int* gbase = lhist;                     // safe: own-slot hist read precedes, 2 barriers apart
    int bx = blockIdx.x, t = threadIdx.x;
    if (bx >= P1B) {
        // fp32->fp16 table conversions, 4 elements/thread
        int cb = bx - P1B;
        if (cb < CONV4E) {
            int i = cb * 1024 + t;
            #pragma unroll
            for (int j = 0; j < 4; ++j) ent_a4[i + j * 256] = f2h(ent0[i + j * 256]);
        } else {
            int i = (cb - CONV4E) * 1024 + t;
            #pragma unroll
            for (int j = 0; j < 4; ++j) {
                int ii = i + j * 256;
                if (ii < N_ITEMS * 16) cf16a4[ii] = f2h(cf0[ii]);
            }
        }
        return;
    }
    int seg = bx / HBLK;
    int tb  = bx % HBLK;
    int tstart = tb * TILE1;
    int valid = min(TILE1, N_EDGES - tstart);
    const int* karr = (seg == 0) ? head : (seg == 1) ? rows : cols;
    int shift = (seg == 0) ? 10 : (seg == 1) ? 9 : 8;
    int* bcur = (seg == 0) ? bcur_e : (seg == 1) ? bcur_u : bcur_i;
    lhist[t] = 0;
    __syncthreads();
    // pass 1: load keys + payloads into registers, build histogram
    int kreg[8], pxr[8], pyr[8];
    #pragma unroll
    for (int j = 0; j < 8; ++j) {
        int i = t + j * 256;
        if (i < valid) {
            int k = karr[tstart + i];
            kreg[j] = k;
            if (seg == 0) {
                pxr[j] = tail[tstart + i] | ((etype[tstart + i] - 1) << 18);
            } else {
                int px;
                if (seg == 1) px = cols[tstart + i] | ((k & 511) << 16);
                else          px = rows[tstart + i] | ((k & 255) << 17);
                pxr[j] = px;
                pyr[j] = f32_to_h16bits(vals[tstart + i]) | ((k >> shift) << 16);
            }
            atomicAdd(&lhist[k >> shift], 1);
        }
    }
    __syncthreads();
    int v = lhist[t];                        // own slot; last read of hist values
    int lane = t & 63, wv = t >> 6;
    int sc = v;
    #pragma unroll
    for (int d = 1; d < 64; d <<= 1) {
        int x = __shfl_up(sc, d, 64);
        if (lane >= d) sc += x;
    }
    if (lane == 63) wsum[wv] = sc;
    __syncthreads();
    if (t == 0) {
        int a = 0;
        #pragma unroll
        for (int i = 0; i < 4; ++i) { wpre[i] = a; a += wsum[i]; }
    }
    __syncthreads();
    int excl = sc + wpre[wv] - v;
    lstart[t] = excl;
    lcur[t] = excl;
    gbase[t] = t * ACAP + atomicAdd(&bcur[t], v);   // overwrites lhist[t] (hist dead)
    __syncthreads();
    if (seg == 0) {
        int* key_st = (int*)pay_st;
        int* ps = key_st + TILE1;
        #pragma unroll
        for (int j = 0; j < 8; ++j) {
            int i = t + j * 256;
            if (i < valid) {
                int sp = atomicAdd(&lcur[kreg[j] >> 10], 1);
                key_st[sp] = kreg[j];
                ps[sp] = pxr[j];
            }
        }
        __syncthreads();
        for (int j = t; j < valid; j += 256) {
            int k = key_st[j];
            int b = k >> 10;
            int pos = gbase[b] + (j - lstart[b]);
            keys_ping[pos] = k;
            kg_ping[pos] = ps[j];
        }
    } else {
        int2* pay = (seg == 1) ? u_ping : i_ping;
        #pragma unroll
        for (int j = 0; j < 8; ++j) {
            int i = t + j * 256;
            if (i < valid) {
                int sp = atomicAdd(&lcur[kreg[j] >> shift], 1);
                pay_st[sp] = make_int2(pxr[j], pyr[j]);
            }
        }
        __syncthreads();
        for (int j = t; j < valid; j += 256) {
            int2 p = pay_st[j];
            int bb = (p.y >> 16) & 0xFF;     // bucket id carried in payload — no search
            int pos = gbase[bb] + (j - lstart[bb]);
            pay[pos] = p;
        }
    }
}

// ------------- phase 2: row offsets + ping->pong scatter (+ angle overlap) -------------
__global__ void __launch_bounds__(256) phase2_angle(
        const int* __restrict__ bcur_e, const int* __restrict__ keys_ping,
        const int* __restrict__ kg_ping, int* __restrict__ kg_pack, int* __restrict__ off_e,
        const int* __restrict__ bcur_u, const int2* __restrict__ u_ping,
        int2* __restrict__ u_pack, int* __restrict__ off_u,
        const int* __restrict__ bcur_i, const int2* __restrict__ i_ping,
        int2* __restrict__ i_pack, int* __restrict__ off_i,
        const half8_t* __restrict__ ent_a, const int* __restrict__ th,
        const int* __restrict__ tt, float* __restrict__ l2blk) {
    __shared__ int hist[1024];
    __shared__ int wsum[4], wpre[4];
    __shared__ float sb[32];
    int t = threadIdx.x;
    if (blockIdx.x >= 3 * NBUCK) {
        angle_body(blockIdx.x - 3 * NBUCK, t, ent_a, th, tt, sb, l2blk);
        return;
    }
    int seg = blockIdx.x / NBUCK;
    int b   = blockIdx.x % NBUCK;
    int bins  = (seg == 0) ? 1024 : (seg == 1) ? 512 : 256;
    int shift = (seg == 0) ? 10 : (seg == 1) ? 9 : 8;
    int n_rows = (seg == 0) ? N_ENTITIES : (seg == 1) ? N_USERS : N_ITEMS;
    const int* bcur = (seg == 0) ? bcur_e : (seg == 1) ? bcur_u : bcur_i;
    int* off = (seg == 0) ? off_e : (seg == 1) ? off_u : off_i;
    int rs = b << shift;
    int re = min(rs + bins, n_rows);
    int nr = re - rs;
    int base = b * ACAP;
    int len = bcur[b];                       // relative cursor = count
    for (int r = t; r < bins; r += 256) hist[r] = 0;
    __syncthreads();
    if (seg == 0) {
        for (int j = t; j < len; j += 256) atomicAdd(&hist[keys_ping[base + j] - rs], 1);
    } else if (seg == 1) {
        for (int j = t; j < len; j += 256) atomicAdd(&hist[(u_ping[base + j].x >> 16) & 511], 1);
    } else {
        for (int j = t; j < len; j += 256) atomicAdd(&hist[(i_ping[base + j].x >> 17) & 255], 1);
    }
    __syncthreads();
    int own = bins >> 8;
    int c[4]; int tot = 0;
    #pragma unroll
    for (int i = 0; i < 4; ++i) { c[i] = (i < own) ? hist[t * own + i] : 0; tot += c[i]; }
    int lane = t & 63, wv = t >> 6;
    int sc = tot;
    #pragma unroll
    for (int d = 1; d < 64; d <<= 1) {
        int x = __shfl_up(sc, d, 64);
        if (lane >= d) sc += x;
    }
    if (lane == 63) wsum[wv] = sc;
    __syncthreads();
    if (t == 0) {
        int a = 0;
        #pragma unroll
        for (int i = 0; i < 4; ++i) { wpre[i] = a; a += wsum[i]; }
    }
    __syncthreads();
    int run = sc + wpre[wv] - tot;
    #pragma unroll
    for (int i = 0; i < 4; ++i) { if (i < own) { hist[t * own + i] = run; run += c[i]; } }
    __syncthreads();
    for (int r = t; r < nr; r += 256) off[rs + b + r] = base + hist[r];
    if (t == 0) off[rs + b + nr] = base + len;
    __syncthreads();
    if (seg == 0) {
        for (int j = t; j < len; j += 256) {
            int k = keys_ping[base + j];
            int slot = atomicAdd(&hist[k - rs], 1);
            kg_pack[base + slot] = kg_ping[base + j];
        }
    } else if (seg == 1) {
        for (int j = t; j < len; j += 256) {
            int2 p = u_ping[base + j];
            int slot = atomicAdd(&hist[(p.x >> 16) & 511], 1);
            u_pack[base + slot] = p;
        }
    } else {
        for (int j = t; j < len; j += 256) {
            int2 p = i_ping[base + j];
            int slot = atomicAdd(&hist[(p.x >> 17) & 255], 1);
            i_pack[base + slot] = p;
        }
    }
}

// ------------------------------ hop bodies ------------------------------
// 4-edge unroll: gathers issued together for MLP; fp16 accumulation order
// (strictly ascending k, one add per edge) identical to the 2-unroll version.
__device__ inline void kg0_body(int bid, int t, const int* __restrict__ off,
                                const int* __restrict__ pack, half8_t* srel,
                                const float* __restrict__ relw,
                                const half8_t* __restrict__ src, half8_t* __restrict__ dst,
                                half8_t* __restrict__ res, const float4* __restrict__ res_init) {
    if (t < (N_REL - 1) * 8) {
        int rel = t >> 3, o = t & 7;
        const float4* r4 = (const float4*)relw;
        srel[rel * 9 + o] = f8_to_h8(f8_from2(r4[rel * 16 + o * 2], r4[rel * 16 + o * 2 + 1]));
    }
    __syncthreads();
    int row = bid * 32 + (t >> 3);
    int o = t & 7;
    int idx = row + (row >> 10);
    int s = off[idx], e = off[idx + 1];
    half8_t acc = h8_zero();
    int k = s;
    for (; k + 4 <= e; k += 4) {
        int p0 = pack[k], p1 = pack[k + 1], p2 = pack[k + 2], p3 = pack[k + 3];
        half8_t a0 = src[(p0 & 0x3FFFF) * 8 + o];
        half8_t a1 = src[(p1 & 0x3FFFF) * 8 + o];
        half8_t a2 = src[(p2 & 0x3FFFF) * 8 + o];
        half8_t a3 = src[(p3 & 0x3FFFF) * 8 + o];
        acc += a0 * srel[(p0 >> 18) * 9 + o];
        acc += a1 * srel[(p1 >> 18) * 9 + o];
        acc += a2 * srel[(p2 >> 18) * 9 + o];
        acc += a3 * srel[(p3 >> 18) * 9 + o];
    }
    for (; k < e; ++k) {
        int p0 = pack[k];
        acc += src[(p0 & 0x3FFFF) * 8 + o] * srel[(p0 >> 18) * 9 + o];
    }
    float8_t f = h8_to_f8(acc);
    f *= 1.0f / fmaxf((float)(e - s), 1.0f);
    float ss = grp_red8(sum_sq8(f));
    f *= 1.0f / fmaxf(sqrtf(ss), 1e-12f);
    dst[row * 8 + o] = f8_to_h8(f);
    if (row < N_ITEMS) {
        float8_t rr = f8_from2(res_init[row * 16 + o * 2], res_init[row * 16 + o * 2 + 1]);
        rr += f;
        res[row * 8 + o] = f8_to_h8(rr);
    }
}

__device__ inline void kg2_body(int bid, int t, const int* __restrict__ off,
                                const int* __restrict__ pack, half8_t* srel,
                                const float* __restrict__ relw,
                                const half8_t* __restrict__ src, half8_t* __restrict__ res) {
    if (t < (N_REL - 1) * 8) {
        int rel = t >> 3, o = t & 7;
        const float4* r4 = (const float4*)relw;
        srel[rel * 9 + o] = f8_to_h8(f8_from2(r4[rel * 16 + o * 2], r4[rel * 16 + o * 2 + 1]));
    }
    __syncthreads();
    int row = bid * 32 + (t >> 3);
    if (row >= N_ITEMS) return;
    int o = t & 7;
    int idx = row + (row >> 10);
    int s = off[idx], e = off[idx + 1];
    half8_t acc = h8_zero();
    int k = s;
    for (; k + 4 <= e; k += 4) {
        int p0 = pack[k], p1 = pack[k + 1], p2 = pack[k + 2], p3 = pack[k + 3];
        half8_t a0 = src[(p0 & 0x3FFFF) * 8 + o];
        half8_t a1 = src[(p1 & 0x3FFFF) * 8 + o];
        half8_t a2 = src[(p2 & 0x3FFFF) * 8 + o];
        half8_t a3 = src[(p3 & 0x3FFFF) * 8 + o];
        acc += a0 * srel[(p0 >> 18) * 9 + o];
        acc += a1 * srel[(p1 >> 18) * 9 + o];
        acc += a2 * srel[(p2 >> 18) * 9 + o];
        acc += a3 * srel[(p3 >> 18) * 9 + o];
    }
    for (; k < e; ++k) {
        int p0 = pack[k];
        acc += src[(p0 & 0x3FFFF) * 8 + o] * srel[(p0 >> 18) * 9 + o];
    }
    float8_t f = h8_to_f8(acc);
    f *= 1.0f / fmaxf((float)(e - s), 1.0f);
    float ss = grp_red8(sum_sq8(f));
    f *= 1.0f / fmaxf(sqrtf(ss), 1e-12f);
    float8_t rr = h8_to_f8(res[row * 8 + o]);
    rr += f;
    float s2 = grp_red8(sum_sq8(rr));
    rr *= 1.0f / fmaxf(sqrtf(s2), 1e-12f);
    res[row * 8 + o] = f8_to_h8(rr);
}

// ucf: software-pipelined payload prefetch — next iteration's payload loads issue
// during this iteration's gather latency. Accumulation order bit-identical.
__device__ inline void ucf_body(int bid, int t, const int* __restrict__ off,
                                const int2* __restrict__ u_pack,
                                const half8_t* __restrict__ cf16,
                                half8_t* __restrict__ ucf) {
    int row = bid * 32 + (t >> 3);
    int o = t & 7;
    int idx = row + (row >> 9);
    int s = off[idx], e = off[idx + 1];
    half8_t acc = h8_zero();
    int k = s;
    if (k + 4 <= e) {
        int2 p0 = u_pack[k], p1 = u_pack[k + 1], p2 = u_pack[k + 2], p3 = u_pack[k + 3];
        for (;;) {
            int kn = k + 4;
            half8_t c0 = cf16[(p0.x & 0xFFFF) * 8 + o];
            half8_t c1 = cf16[(p1.x & 0xFFFF) * 8 + o];
            half8_t c2 = cf16[(p2.x & 0xFFFF) * 8 + o];
            half8_t c3 = cf16[(p3.x & 0xFFFF) * 8 + o];
            bool more = (kn + 4 <= e);
            int2 n0, n1, n2, n3;
            if (more) { n0 = u_pack[kn]; n1 = u_pack[kn + 1]; n2 = u_pack[kn + 2]; n3 = u_pack[kn + 3]; }
            acc += c0 * h16_from_bits(p0.y);
            acc += c1 * h16_from_bits(p1.y);
            acc += c2 * h16_from_bits(p2.y);
            acc += c3 * h16_from_bits(p3.y);
            k = kn;
            if (!more) break;
            p0 = n0; p1 = n1; p2 = n2; p3 = n3;
        }
    }
    for (; k < e; ++k) {
        int2 p0 = u_pack[k];
        acc += cf16[(p0.x & 0xFFFF) * 8 + o] * h16_from_bits(p0.y);
    }
    ucf[row * 8 + o] = acc;
}

__device__ inline void ubatch_body(int bid, int t, const int* __restrict__ user,
                                   const int* __restrict__ off,
                                   const int2* __restrict__ u_pack,
                                   const half8_t* __restrict__ ent_a,
                                   const half8_t* __restrict__ ent_b,
                                   const float4* __restrict__ usr0f,
                                   half8_t* __restrict__ usr_b) {
    int g = t >> 3, o = t & 7;
    int b = bid * 32 + g;
    int uid = user[b];
    int idx = uid + (uid >> 9);
    int s = off[idx], e = off[idx + 1];
    half8_t acc1 = h8_zero(), acc2 = h8_zero();
    int k = s;
    for (; k + 4 <= e; k += 4) {
        int2 p0 = u_pack[k], p1 = u_pack[k + 1], p2 = u_pack[k + 2], p3 = u_pack[k + 3];
        int c0 = (p0.x & 0xFFFF) * 8 + o;
        int c1 = (p1.x & 0xFFFF) * 8 + o;
        int c2 = (p2.x & 0xFFFF) * 8 + o;
        int c3 = (p3.x & 0xFFFF) * 8 + o;
        half8_t ea0 = ent_a[c0], eb0 = ent_b[c0];
        half8_t ea1 = ent_a[c1], eb1 = ent_b[c1];
        half8_t ea2 = ent_a[c2], eb2 = ent_b[c2];
        half8_t ea3 = ent_a[c3], eb3 = ent_b[c3];
        _Float16 v0 = h16_from_bits(p0.y);
        _Float16 v1 = h16_from_bits(p1.y);
        _Float16 v2 = h16_from_bits(p2.y);
        _Float16 v3 = h16_from_bits(p3.y);
        acc1 += ea0 * v0; acc2 += eb0 * v0;
        acc1 += ea1 * v1; acc2 += eb1 * v1;
        acc1 += ea2 * v2; acc2 += eb2 * v2;
        acc1 += ea3 * v3; acc2 += eb3 * v3;
    }
    for (; k < e; ++k) {
        int2 p0 = u_pack[k];
        int c0 = (p0.x & 0xFFFF) * 8 + o;
        _Float16 v0 = h16_from_bits(p0.y);
        acc1 += ent_a[c0] * v0;
        acc2 += ent_b[c0] * v0;
    }
    float8_t f1 = h8_to_f8(acc1);
    float ss1 = grp_red8(sum_sq8(f1));
    f1 *= 1.0f / fmaxf(sqrtf(ss1), 1e-12f);
    float8_t u0 = f8_from2(usr0f[uid * 16 + o * 2], usr0f[uid * 16 + o * 2 + 1]);
    float8_t r1 = h8_to_f8(f8_to_h8(u0 + f1));   // fp16 round-trip (matches hop-1 store)
    float8_t f2 = h8_to_f8(acc2);
    float ss2 = grp_red8(sum_sq8(f2));
    f2 *= 1.0f / fmaxf(sqrtf(ss2), 1e-12f);
    float8_t r = r1 + f2;
    float s3 = grp_red8(sum_sq8(r));
    r *= 1.0f / fmaxf(sqrtf(s3), 1e-12f);
    usr_b[b * 8 + o] = f8_to_h8(r);
}

// item: software-pipelined payload prefetch (deg ~20 -> ~5 iterations, biggest win).
__device__ inline void item_body(int bid, int t, const int* __restrict__ off,
                                 const int2* __restrict__ i_pack,
                                 const half8_t* __restrict__ ucf,
                                 half8_t* __restrict__ cf_nxt, half8_t* __restrict__ res,
                                 const float4* __restrict__ res_init, int first, int last) {
    int row = bid * 32 + (t >> 3);
    int o = t & 7;
    if (row >= N_ITEMS) return;
    int idx = row + (row >> 8);
    int s = off[idx], e = off[idx + 1];
    half8_t acc = h8_zero();
    int k = s;
    if (k + 4 <= e) {
        int2 p0 = i_pack[k], p1 = i_pack[k + 1], p2 = i_pack[k + 2], p3 = i_pack[k + 3];
        for (;;) {
            int kn = k + 4;
            half8_t c0 = ucf[(p0.x & 0x1FFFF) * 8 + o];
            half8_t c1 = ucf[(p1.x & 0x1FFFF) * 8 + o];
            half8_t c2 = ucf[(p2.x & 0x1FFFF) * 8 + o];
            half8_t c3 = ucf[(p3.x & 0x1FFFF) * 8 + o];
            bool more = (kn + 4 <= e);
            int2 n0, n1, n2, n3;
            if (more) { n0 = i_pack[kn]; n1 = i_pack[kn + 1]; n2 = i_pack[kn + 2]; n3 = i_pack[kn + 3]; }
            acc += c0 * h16_from_bits(p0.y);
            acc += c1 * h16_from_bits(p1.y);
            acc += c2 * h16_from_bits(p2.y);
            acc += c3 * h16_from_bits(p3.y);
            k = kn;
            if (!more) break;
            p0 = n0; p1 = n1; p2 = n2; p3 = n3;
        }
    }
    for (; k < e; ++k) {
        int2 p0 = i_pack[k];
        acc += ucf[(p0.x & 0x1FFFF) * 8 + o] * h16_from_bits(p0.y);
    }
    float8_t f = h8_to_f8(acc);
    float ss = grp_red8(sum_sq8(f));
    f *= 1.0f / fmaxf(sqrtf(ss), 1e-12f);
    if (!last) cf_nxt[row * 8 + o] = f8_to_h8(f);
    float8_t rr;
    if (first) rr = f8_from2(res_init[row * 16 + o * 2], res_init[row * 16 + o * 2 + 1]);
    else       rr = h8_to_f8(res[row * 8 + o]);
    rr += f;
    if (last) {
        float s2 = grp_red8(sum_sq8(rr));
        rr *= 1.0f / fmaxf(sqrtf(s2), 1e-12f);
    }
    res[row * 8 + o] = f8_to_h8(rr);
}

// loss halves — 16 negatives per round for MLP; accumulation order unchanged
__device__ inline void loss_ent_body(int b, int t,
                                     const int* __restrict__ pos, const int* __restrict__ neg,
                                     const half4_t* __restrict__ usrb4,
                                     const half4_t* __restrict__ ent4,
                                     float* __restrict__ dpe, float* __restrict__ l1pe) {
    int lane = t & 63;
    int g = lane >> 4, q = lane & 15;
    int pid = pos[b];
    float4 u = h2f(usrb4[b * 16 + q]);
    float4 p = h2f(ent4[pid * 16 + q]);
    float dpe_v = grp_red16(dot4(u, p));
    float sum_n = 0.f, cnt_n = 0.f;
    const int* nb = neg + b * NUM_NEG;
    for (int j = 0; j < NUM_NEG; j += 16) {
        int n0 = nb[j + g], n1 = nb[j + 4 + g], n2 = nb[j + 8 + g], n3 = nb[j + 12 + g];
        float4 e0 = h2f(ent4[n0 * 16 + q]);
        float4 e1 = h2f(ent4[n1 * 16 + q]);
        float4 e2 = h2f(ent4[n2 * 16 + q]);
        float4 e3 = h2f(ent4[n3 * 16 + q]);
        float dn0 = grp_red16(dot4(u, e0));
        float dn1 = grp_red16(dot4(u, e1));
        float dn2 = grp_red16(dot4(u, e2));
        float dn3 = grp_red16(dot4(u, e3));
        float s0 = fmaxf(dn0 - MARGIN_CCL, 0.f); sum_n += s0; if (s0 > 0.f) cnt_n += 1.f;
        float s1 = fmaxf(dn1 - MARGIN_CCL, 0.f); sum_n += s1; if (s1 > 0.f) cnt_n += 1.f;
        float s2 = fmaxf(dn2 - MARGIN_CCL, 0.f); sum_n += s2; if (s2 > 0.f) cnt_n += 1.f;
        float s3 = fmaxf(dn3 - MARGIN_CCL, 0.f); sum_n += s3; if (s3 > 0.f) cnt_n += 1.f;
    }
    sum_n = cross_grp_scalar(sum_n); cnt_n = cross_grp_scalar(cnt_n);
    if (lane == 0) {
        dpe[b] = dpe_v;
        l1pe[b] = sum_n / (cnt_n + 1e-5f);
    }
}

__global__ void __launch_bounds__(256) loss_cf_kernel(
        const int* __restrict__ pos, const int* __restrict__ neg,
        const half4_t* __restrict__ usrb4, const half4_t* __restrict__ cf4,
        const float* __restrict__ dpe, const float* __restrict__ l1pe,
        float* __restrict__ l1p) {
    int b = blockIdx.x * 4 + (threadIdx.x >> 6);
    int lane = threadIdx.x & 63;
    int g = lane >> 4, q = lane & 15;
    int pid = pos[b];
    float4 u = h2f(usrb4[b * 16 + q]);
    float4 pc = h2f(cf4[pid * 16 + q]);
    float dpc = grp_red16(dot4(u, pc));
    float sum_c = 0.f, cnt_c = 0.f;
    const int* nb = neg + b * NUM_NEG;
    for (int j = 0; j < NUM_NEG; j += 16) {
        int n0 = nb[j + g], n1 = nb[j + 4 + g], n2 = nb[j + 8 + g], n3 = nb[j + 12 + g];
        float4 e0 = h2f(cf4[n0 * 16 + q]);
        float4 e1 = h2f(cf4[n1 * 16 + q]);
        float4 e2 = h2f(cf4[n2 * 16 + q]);
        float4 e3 = h2f(cf4[n3 * 16 + q]);
        float dc0 = grp_red16(dot4(u, e0));
        float dc1 = grp_red16(dot4(u, e1));
        float dc2 = grp_red16(dot4(u, e2));
        float dc3 = grp_red16(dot4(u, e3));
        float t0 = fmaxf(dc0 - MARGIN_CCL, 0.f); sum_c += t0; if (t0 > 0.f) cnt_c += 1.f;
        float t1 = fmaxf(dc1 - MARGIN_CCL, 0.f); sum_c += t1; if (t1 > 0.f) cnt_c += 1.f;
        float t2 = fmaxf(dc2 - MARGIN_CCL, 0.f); sum_c += t2; if (t2 > 0.f) cnt_c += 1.f;
        float t3 = fmaxf(dc3 - MARGIN_CCL, 0.f); sum_c += t3; if (t3 > 0.f) cnt_c += 1.f;
    }
    sum_c = cross_grp_scalar(sum_c); cnt_c = cross_grp_scalar(cnt_c);
    if (lane == 0) {
        float ui_pos = fmaxf(2.0f - dpe[b] - dpc, 0.0f);
        l1p[b] = ui_pos + l1pe[b] + sum_c / (cnt_c + 1e-5f);
    }
}

// --------------------------- fused launches ---------------------------
// kg0 (full) + ucf0 (cf-only, all users)
__global__ void __launch_bounds__(256) fused_h0(
        const int* __restrict__ off_e, const int* __restrict__ kg_pack,
        const float* __restrict__ relw, const half8_t* __restrict__ ent_a,
        half8_t* __restrict__ ent_b, half8_t* __restrict__ ent_res,
        const float4* __restrict__ ent0f,
        const int* __restrict__ off_u, const int2* __restrict__ u_pack,
        const half8_t* __restrict__ cf16_a, half8_t* __restrict__ ucf) {
    __shared__ half8_t srel[(N_REL - 1) * 9];
    int bx = blockIdx.x, t = threadIdx.x;
    if (bx < KGB) {
        kg0_body(bx, t, off_e, kg_pack, srel, relw, ent_a, ent_b, ent_res, ent0f);
    } else {
        ucf_body(bx - KGB, t, off_u, u_pack, cf16_a, ucf);
    }
}

// kg1 (item rows only) + item0 + batch-user embedding
__global__ void __launch_bounds__(256) fused_ik(
        const int* __restrict__ off_e, const int* __restrict__ kg_pack,
        const float* __restrict__ relw, const half8_t* __restrict__ ent_b,
        half8_t* __restrict__ ent_res,
        const int* __restrict__ off_i, const int2* __restrict__ i_pack,
        const half8_t* __restrict__ ucf, half8_t* __restrict__ cf16_b,
        half8_t* __restrict__ cf_res, const float4* __restrict__ cf0f,
        const int* __restrict__ user, const int* __restrict__ off_u,
        const int2* __restrict__ u_pack, const half8_t* __restrict__ ent_a,
        const float4* __restrict__ usr0f, half8_t* __restrict__ usr_b) {
    __shared__ half8_t srel[(N_REL - 1) * 9];
    int bx = blockIdx.x, t = threadIdx.x;
    if (bx < ITEMB) {
        kg2_body(bx, t, off_e, kg_pack, srel, relw, ent_b, ent_res);
    } else if (bx < 2 * ITEMB) {
        item_body(bx - ITEMB, t, off_i, i_pack, ucf, cf16_b, cf_res, cf0f, 1, 0);
    } else {
        ubatch_body(bx - 2 * ITEMB, t, user, off_u, u_pack, ent_a, ent_b, usr0f, usr_b);
    }
}

// ucf hop-1 (from cf1) + ent-half loss
__global__ void __launch_bounds__(256) fused_u1_loss(
        const int* __restrict__ off_u, const int2* __restrict__ u_pack,
        const half8_t* __restrict__ cf16_b, half8_t* __restrict__ ucf,
        const int* __restrict__ pos, const int* __restrict__ neg,
        const half4_t* __restrict__ usrb4, const half4_t* __restrict__ ent4,
        float* __restrict__ dpe, float* __restrict__ l1pe) {
    int bx = blockIdx.x, t = threadIdx.x;
    if (bx < UCFB) {
        ucf_body(bx, t, off_u, u_pack, cf16_b, ucf);
    } else {
        int b = (bx - UCFB) * 4 + (t >> 6);
        loss_ent_body(b, t, pos, neg, usrb4, ent4, dpe, l1pe);
    }
}

__global__ void __launch_bounds__(256) item_h1(
        const int* __restrict__ off_i, const int2* __restrict__ i_pack,
        const half8_t* __restrict__ ucf, half8_t* __restrict__ cf_res,
        const float4* __restrict__ cf0f) {
    item_body(blockIdx.x, threadIdx.x, off_i, i_pack, ucf, (half8_t*)0, cf_res, cf0f, 0, 1);
}

__global__ void finalize_kernel(const float* __restrict__ l1p, const float* __restrict__ l2b,
                                float* __restrict__ out) {
    __shared__ float sb[1024];
    float a1 = 0.f;
    for (int i = threadIdx.x; i < BATCH; i += 1024) a1 += l1p[i];
    float a2 = 0.f;
    for (int i = threadIdx.x; i < ANGB; i += 1024) a2 += l2b[i];
    sb[threadIdx.x] = a1 / (float)BATCH + ANGLE_W * a2 / (float)N_TRIPLETS;
    __syncthreads();
    for (int s = 512; s > 0; s >>= 1) {
        if (threadIdx.x < s) sb[threadIdx.x] += sb[threadIdx.x + s];
        __syncthreads();
    }
    if (threadIdx.x == 0) out[0] = sb[0];
}

extern "C" void kernel_launch(void* const* d_in, const int* in_sizes, int n_in,
                              void* d_out, int out_size, void* d_ws, size_t ws_size,
                              hipStream_t stream) {
    const float* all_embed = (const float*)d_in[0];
    const float* item_cf0  = (const float*)d_in[1];
    const float* relw      = (const float*)d_in[2];
    const float* vals      = (const float*)d_in[3];
    const int* user        = (const int*)d_in[4];
    const int* pos_item    = (const int*)d_in[5];
    const int* neg_item    = (const int*)d_in[6];
    const int* edge_head   = (const int*)d_in[7];
    const int* edge_tail   = edge_head + N_EDGES;
    const int* etype       = (const int*)d_in[8];
    const int* irows       = (const int*)d_in[9];
    const int* icols       = (const int*)d_in[10];
    const int* th          = (const int*)d_in[11];
    const int* tt          = (const int*)d_in[12];
    float* out             = (float*)d_out;

    char* base = (char*)d_ws;
    size_t woff = 0;
    auto alloc = [&](size_t bytes) -> void* {
        void* p = base + woff;
        woff = (woff + bytes + 255) & ~(size_t)255;
        return p;
    };
    const size_t ping_ui = (size_t)NBUCK * ACAP * 8;    // 12,845,056 B
    const size_t ping_kg = (size_t)NBUCK * ACAP * 4;    // 6,422,528 B

    half8_t* ent_a   = (half8_t*)alloc((size_t)N_ENTITIES * EMB * 2);
    // ent_b hosts the u/i ping arenas before fused_h0 writes it (bumped to fit both)
    half8_t* ent_b   = (half8_t*)alloc(2 * ping_ui);
    half8_t* cf16_a  = (half8_t*)alloc((size_t)N_ITEMS * EMB * 2);
    // cf16_b hosts the kg payload ping before fused_ik writes it (bumped)
    half8_t* cf16_b  = (half8_t*)alloc(ping_kg);
    // ucf hosts the kg keys ping before fused_h0 writes it (12.8 MB >= 6.42 MB)
    half8_t* ucf     = (half8_t*)alloc((size_t)N_USERS * EMB * 2);
    half8_t* ent_res = (half8_t*)alloc((size_t)N_ITEMS * EMB * 2);
    half8_t* cf_res  = (half8_t*)alloc((size_t)N_ITEMS * EMB * 2);
    half8_t* usr_b   = (half8_t*)alloc((size_t)BATCH * EMB * 2);
    int2* u_pack     = (int2*)alloc(ping_ui);
    int2* i_pack     = (int2*)alloc(ping_ui);
    int* kg_pack     = (int*)alloc(ping_kg);
    float* l1p       = (float*)alloc((size_t)BATCH * 4);
    float* dpe       = (float*)alloc((size_t)BATCH * 4);
    float* l1pe      = (float*)alloc((size_t)BATCH * 4);
    float* l2blk     = (float*)alloc((size_t)ANGB * 4);
    int* off_e       = (int*)alloc((size_t)(N_ENTITIES + NBUCK + 1) * 4);
    int* off_u       = (int*)alloc((size_t)(N_USERS + NBUCK + 1) * 4);
    int* off_i       = (int*)alloc((size_t)(N_ITEMS + NBUCK + 1) * 4);
    int* bcur_all    = (int*)alloc(3 * 256 * 4);
    int* bcur_e      = bcur_all;
    int* bcur_u      = bcur_all + 256;
    int* bcur_i      = bcur_all + 512;

    // ping aliases (lifetimes: written phase1, read phase2, dead before host write)
    int2* u_ping   = (int2*)ent_b;
    int2* i_ping   = (int2*)((char*)ent_b + ping_ui);
    int* kg_ping   = (int*)cf16_b;
    int* keys_ping = (int*)ucf;

    const float* ent0 = all_embed + (size_t)N_USERS * EMB;

    // 1) zero relative arena cursors (capture-safe async memset)
    hipMemsetAsync(bcur_all, 0, 3 * 256 * 4, stream);
    // 2) phase 1 placement into pings + fp32->fp16 conversions (overlapped)
    phase1_sort<<<P1B + CONV4E + CONV4I, 256, 0, stream>>>(
        edge_head, edge_tail, etype, irows, icols, vals,
        bcur_e, bcur_u, bcur_i, keys_ping, kg_ping, u_ping, i_ping,
        (const float4*)ent0, (const float4*)item_cf0, (half4_t*)ent_a, (half4_t*)cf16_a);
    // 3) phase 2: row offsets + ping->pong scatter, angle blocks as filler
    phase2_angle<<<3 * NBUCK + ANGB, 256, 0, stream>>>(
        bcur_e, keys_ping, kg_ping, kg_pack, off_e,
        bcur_u, u_ping, u_pack, off_u,
        bcur_i, i_ping, i_pack, off_i,
        (const half8_t*)ent_a, th, tt, l2blk);
    // 4) kg0 (full) + ucf0
    fused_h0<<<KGB + UCFB, 256, 0, stream>>>(
        off_e, kg_pack, relw, ent_a, ent_b, ent_res, (const float4*)ent0,
        off_u, u_pack, cf16_a, ucf);
    // 5) kg1 (items only) + item0 + batch-user embedding
    fused_ik<<<2 * ITEMB + UBB, 256, 0, stream>>>(
        off_e, kg_pack, relw, ent_b, ent_res,
        off_i, i_pack, ucf, cf16_b, cf_res, (const float4*)item_cf0,
        user, off_u, u_pack, ent_a, (const float4*)all_embed, usr_b);
    // 6) ucf1 (from cf1) + ent-half loss
    fused_u1_loss<<<UCFB + LOSSB, 256, 0, stream>>>(
        off_u, u_pack, cf16_b, ucf, pos_item, neg_item,
        (const half4_t*)usr_b, (const half4_t*)ent_res, dpe, l1pe);
    // 7) item1 (final cf_res)
    item_h1<<<ITEMB, 256, 0, stream>>>(off_i, i_pack, ucf, cf_res,
                                       (const float4*)item_cf0);
    // 8) cf-half loss + combine
    loss_cf_kernel<<<LOSSB, 256, 0, stream>>>(pos_item, neg_item,
                                              (const half4_t*)usr_b, (const half4_t*)cf_res,
                                              dpe, l1pe, l1p);
    // 9) final reduction
    finalize_kernel<<<1, 1024, 0, stream>>>(l1p, l2blk, out);
}